// Round 1
// baseline (401.518 us; speedup 1.0000x reference)
//
#include <hip/hip_runtime.h>
#include <stdint.h>

// ---------------- constants ----------------
constexpr int Bq = 8, Nn = 1025, Dd = 768, Hh = 12, HDd = 64, Pp = 1024;
constexpr int NP = 1088;              // padded N = 17*64
constexpr int MROWS = Bq * Nn;        // 8200
constexpr float EPSI = 1e-6f;

typedef __attribute__((ext_vector_type(8))) short bfrag;   // 8 bf16 = 4 VGPR
typedef __attribute__((ext_vector_type(4))) float ffrag;   // 4 f32
typedef __attribute__((ext_vector_type(4))) float f4;
typedef __attribute__((ext_vector_type(4))) unsigned short us4;

#define MFMA16(a, b, c) __builtin_amdgcn_mfma_f32_16x16x32_bf16((a), (b), (c), 0, 0, 0)

__device__ __forceinline__ unsigned short f2bf(float f) {
  union { float f; uint32_t u; } v{f};
  uint32_t u = v.u;
  return (unsigned short)((u + 0x7fffu + ((u >> 16) & 1u)) >> 16);  // RNE
}
__device__ __forceinline__ float bf2f(unsigned short s) {
  union { uint32_t u; float f; } v; v.u = ((uint32_t)s) << 16; return v.f;
}

// ---------------- fp32 -> bf16 conversion ----------------
__global__ __launch_bounds__(256) void conv_kernel(const float* __restrict__ src,
                                                   unsigned short* __restrict__ dst, int n4) {
  int idx = blockIdx.x * blockDim.x + threadIdx.x;
  int stride = gridDim.x * blockDim.x;
  for (int i = idx; i < n4; i += stride) {
    f4 v = ((const f4*)src)[i];
    us4 o; o[0] = f2bf(v[0]); o[1] = f2bf(v[1]); o[2] = f2bf(v[2]); o[3] = f2bf(v[3]);
    ((us4*)dst)[i] = o;
  }
}

// ---------------- pw = t / (sum(t)+eps) ----------------
__global__ __launch_bounds__(256) void pw_kernel(const float* __restrict__ tr, float* __restrict__ pw) {
  int b = blockIdx.x;
  __shared__ float red[256];
  float s = 0.f;
  for (int j = threadIdx.x; j < Pp; j += 256) s += tr[b * Pp + j];
  red[threadIdx.x] = s; __syncthreads();
  for (int o = 128; o > 0; o >>= 1) { if (threadIdx.x < o) red[threadIdx.x] += red[threadIdx.x + o]; __syncthreads(); }
  float inv = 1.f / (red[0] + EPSI);
  for (int j = threadIdx.x; j < Pp; j += 256) pw[b * Pp + j] = tr[b * Pp + j] * inv;
}

// ---------------- mask bf16 [B][NP][NP], zero padded ----------------
__global__ __launch_bounds__(256) void mask_kernel(const float* __restrict__ graph,
                                                   const float* __restrict__ pw,
                                                   unsigned short* __restrict__ mask) {
  int i = blockIdx.x, b = blockIdx.y;
  unsigned short* mrow = mask + ((size_t)b * NP + i) * NP;
  if (i >= Nn) { for (int j = threadIdx.x; j < NP; j += 256) mrow[j] = 0; return; }
  if (i == 0) {
    for (int j = threadIdx.x; j < NP; j += 256) {
      float v = (j == 0) ? 1.f : (j <= Pp ? pw[b * Pp + j - 1] : 0.f);
      mrow[j] = f2bf(v);
    }
  } else {
    const float* grow = graph + ((size_t)b * Pp + (i - 1)) * Pp;
    for (int j = threadIdx.x; j < NP; j += 256) {
      float v = (j == 0) ? pw[b * Pp + i - 1] : (j <= Pp ? grow[j - 1] : 0.f);
      mrow[j] = f2bf(v);
    }
  }
}

// ---------------- zero pad rows of Q/K and pad cols of VT ----------------
__global__ __launch_bounds__(256) void padzero_kernel(unsigned short* __restrict__ Qo,
                                                      unsigned short* __restrict__ Ko,
                                                      unsigned short* __restrict__ Vo) {
  int bh = blockIdx.x;  // 0..95
  unsigned short* qp = Qo + ((size_t)bh * NP + Nn) * 64;
  unsigned short* kp = Ko + ((size_t)bh * NP + Nn) * 64;
  for (int idx = threadIdx.x; idx < (NP - Nn) * 64; idx += 256) { qp[idx] = 0; kp[idx] = 0; }
  unsigned short* vp = Vo + (size_t)bh * 64 * NP;
  for (int idx = threadIdx.x; idx < 64 * (NP - Nn); idx += 256) {
    int d = idx / (NP - Nn), j = Nn + (idx - d * (NP - Nn));
    vp[(size_t)d * NP + j] = 0;
  }
}

// ---------------- GEMM core: 128x128 tile, BK=64, K=768, bf16 MFMA ----------------
// LDS layout: A tile [128][64] bf16 swizzled (chunk c of row r stored at pos c^(r&7)), B at +1024 uint4.
__device__ __forceinline__ void gemm_main(const unsigned short* __restrict__ A, int rowA0, int rowAmax,
                                          const unsigned short* __restrict__ Bw, int rowB0,
                                          uint4* lds, ffrag acc[4][4], int tid) {
  const int l = tid & 63, lm = l & 15, lg = l >> 4, w = tid >> 6, wr = w >> 1, wc = w & 1;
  const unsigned short* aS[4]; const unsigned short* bS[4];
  int aD[4], bD[4];
#pragma unroll
  for (int q = 0; q < 4; q++) {
    int c = tid + 256 * q, r = c >> 3, p = c & 7, g = p ^ (r & 7);
    int ra = rowA0 + r; if (ra > rowAmax) ra = rowAmax;
    aS[q] = A + (size_t)ra * 768 + 8 * g;  aD[q] = c;
    bS[q] = Bw + (size_t)(rowB0 + r) * 768 + 8 * g;  bD[q] = 1024 + c;
  }
#pragma unroll 1
  for (int kt = 0; kt < 12; kt++) {
    uint4 va[4], vb[4];
#pragma unroll
    for (int q = 0; q < 4; q++) { va[q] = *(const uint4*)aS[q]; vb[q] = *(const uint4*)bS[q]; aS[q] += 64; bS[q] += 64; }
    __syncthreads();
#pragma unroll
    for (int q = 0; q < 4; q++) { lds[aD[q]] = va[q]; lds[bD[q]] = vb[q]; }
    __syncthreads();
    const bfrag* LA = (const bfrag*)lds;
    const bfrag* LB = (const bfrag*)(lds + 1024);
    bfrag af[4][2], bf_[4][2];
#pragma unroll
    for (int am = 0; am < 4; am++) {
      int row = wr * 64 + am * 16 + lm;
      af[am][0] = LA[row * 8 + ((0 + lg) ^ (row & 7))];
      af[am][1] = LA[row * 8 + ((4 + lg) ^ (row & 7))];
    }
#pragma unroll
    for (int an = 0; an < 4; an++) {
      int row = wc * 64 + an * 16 + lm;
      bf_[an][0] = LB[row * 8 + ((0 + lg) ^ (row & 7))];
      bf_[an][1] = LB[row * 8 + ((4 + lg) ^ (row & 7))];
    }
#pragma unroll
    for (int am = 0; am < 4; am++)
#pragma unroll
      for (int an = 0; an < 4; an++) {
        acc[am][an] = MFMA16(af[am][0], bf_[an][0], acc[am][an]);
        acc[am][an] = MFMA16(af[am][1], bf_[an][1], acc[am][an]);
      }
  }
}

// ---------------- kernel 1: QKV GEMM + scatter epilogue ----------------
__global__ __launch_bounds__(256) void qkv_gemm_kernel(const unsigned short* __restrict__ X,
                                                       const unsigned short* __restrict__ W,
                                                       const float* __restrict__ bias,
                                                       unsigned short* __restrict__ Qo,
                                                       unsigned short* __restrict__ Ko,
                                                       unsigned short* __restrict__ Vo) {
  __shared__ uint4 lds[2048];
  int tid = threadIdx.x;
  ffrag zero4 = {0.f, 0.f, 0.f, 0.f};
  ffrag acc[4][4];
#pragma unroll
  for (int i = 0; i < 4; i++)
#pragma unroll
    for (int j = 0; j < 4; j++) acc[i][j] = zero4;
  gemm_main(X, blockIdx.x * 128, MROWS - 1, W, blockIdx.y * 128, lds, acc, tid);
  const int l = tid & 63, lm = l & 15, lg = l >> 4, w = tid >> 6, wr = w >> 1, wc = w & 1;
#pragma unroll
  for (int an = 0; an < 4; an++) {
    int gc = blockIdx.y * 128 + wc * 64 + an * 16 + lm;
    int which = gc / 768, rr = gc - which * 768, h = rr >> 6, hd = rr & 63;
    float bv = bias[gc];
#pragma unroll
    for (int am = 0; am < 4; am++) {
      int grb = blockIdx.x * 128 + wr * 64 + am * 16 + 4 * lg;
#pragma unroll
      for (int r = 0; r < 4; r++) {
        int gr = grb + r;
        if (gr >= MROWS) continue;
        int b = gr / Nn, i = gr - b * Nn;
        size_t bh = (size_t)(b * Hh + h);
        float v = acc[am][an][r] + bv;
        if (which == 0)      Qo[(bh * NP + i) * 64 + hd] = f2bf(v * 0.125f);  // fold HD^-0.5
        else if (which == 1) Ko[(bh * NP + i) * 64 + hd] = f2bf(v);
        else                 Vo[(bh * 64 + hd) * NP + i] = f2bf(v);           // V transposed
      }
    }
  }
}

// ---------------- kernel 3: proj GEMM + bias -> fp32 out ----------------
__global__ __launch_bounds__(256) void proj_gemm_kernel(const unsigned short* __restrict__ A,
                                                        const unsigned short* __restrict__ W,
                                                        const float* __restrict__ bias,
                                                        float* __restrict__ out) {
  __shared__ uint4 lds[2048];
  int tid = threadIdx.x;
  ffrag zero4 = {0.f, 0.f, 0.f, 0.f};
  ffrag acc[4][4];
#pragma unroll
  for (int i = 0; i < 4; i++)
#pragma unroll
    for (int j = 0; j < 4; j++) acc[i][j] = zero4;
  gemm_main(A, blockIdx.x * 128, MROWS - 1, W, blockIdx.y * 128, lds, acc, tid);
  const int l = tid & 63, lm = l & 15, lg = l >> 4, w = tid >> 6, wr = w >> 1, wc = w & 1;
#pragma unroll
  for (int an = 0; an < 4; an++) {
    int gc = blockIdx.y * 128 + wc * 64 + an * 16 + lm;
    float bv = bias[gc];
#pragma unroll
    for (int am = 0; am < 4; am++) {
      int grb = blockIdx.x * 128 + wr * 64 + am * 16 + 4 * lg;
#pragma unroll
      for (int r = 0; r < 4; r++) {
        int gr = grb + r;
        if (gr >= MROWS) continue;
        out[(size_t)gr * 768 + gc] = acc[am][an][r] + bv;
      }
    }
  }
}

// ---------------- kernel 2: fused masked attention (flash-style) ----------------
// block: 4 waves x 16 q-rows = 64 rows. KV tiles of 64. Q pre-scaled.
// out = O / (T + eps*Z) with O=sum e^{s-m}*mask*v, T=sum e^{s-m}*mask, Z=sum e^{s-m}.
__global__ __launch_bounds__(256) void attn_kernel(const unsigned short* __restrict__ Qg,
                                                   const unsigned short* __restrict__ Kg,
                                                   const unsigned short* __restrict__ Vg,
                                                   const unsigned short* __restrict__ Mg,
                                                   unsigned short* __restrict__ Og) {
  __shared__ uint4 smem[1536];  // K 8KB | V 8KB | P 4x2KB
  int tid = threadIdx.x, w = tid >> 6, l = tid & 63, lm = l & 15, lg = l >> 4;
  int ib = blockIdx.x, h = blockIdx.y, b = blockIdx.z;
  size_t bh = (size_t)(b * Hh + h);
  const unsigned short* Qb = Qg + bh * NP * 64;
  const unsigned short* Kb = Kg + bh * NP * 64;
  const unsigned short* Vb = Vg + bh * 64 * NP;
  const unsigned short* Mb = Mg + (size_t)b * NP * NP;
  int i0 = ib * 64 + w * 16;

  bfrag qf0 = *(const bfrag*)(Qb + (size_t)(i0 + lm) * 64 + 8 * lg);
  bfrag qf1 = *(const bfrag*)(Qb + (size_t)(i0 + lm) * 64 + 32 + 8 * lg);

  ffrag zero4 = {0.f, 0.f, 0.f, 0.f};
  ffrag oacc[4] = {zero4, zero4, zero4, zero4};
  float mrun[4] = {-1e30f, -1e30f, -1e30f, -1e30f};
  float Zp[4] = {0.f, 0.f, 0.f, 0.f}, Tp[4] = {0.f, 0.f, 0.f, 0.f};

  int rS = tid >> 3, pS = tid & 7, gS = pS ^ (rS & 7);
  const unsigned short* kS = Kb + rS * 64 + 8 * gS;
  const unsigned short* vS = Vb + (size_t)rS * NP + 8 * gS;
  uint4* ldsK4 = smem; uint4* ldsV4 = smem + 512;
  unsigned short* Pl = (unsigned short*)(smem + 1024 + w * 128);
  const bfrag* LK = (const bfrag*)ldsK4;
  const bfrag* LV = (const bfrag*)ldsV4;
  const bfrag* LP = (const bfrag*)Pl;

#pragma unroll 1
  for (int t = 0; t < 17; t++) {
    uint4 k0 = *(const uint4*)kS, k1 = *(const uint4*)(kS + 2048);
    uint4 v0 = *(const uint4*)vS, v1 = *(const uint4*)(vS + 32 * NP);
    __syncthreads();
    ldsK4[tid] = k0; ldsK4[tid + 256] = k1; ldsV4[tid] = v0; ldsV4[tid + 256] = v1;
    __syncthreads();
    kS += 64 * 64; vS += 64;

    // --- QK^T ---
    ffrag s[4];
#pragma unroll
    for (int jm = 0; jm < 4; jm++) {
      int row = jm * 16 + lm;
      bfrag b0 = LK[row * 8 + ((0 + lg) ^ (row & 7))];
      bfrag b1 = LK[row * 8 + ((4 + lg) ^ (row & 7))];
      ffrag a = zero4;
      a = MFMA16(qf0, b0, a);
      a = MFMA16(qf1, b1, a);
      s[jm] = a;
    }
    // --- online softmax bookkeeping ---
    float al[4];
#pragma unroll
    for (int r = 0; r < 4; r++) {
      float v = fmaxf(fmaxf(s[0][r], s[1][r]), fmaxf(s[2][r], s[3][r]));
      v = fmaxf(v, __shfl_xor(v, 1));
      v = fmaxf(v, __shfl_xor(v, 2));
      v = fmaxf(v, __shfl_xor(v, 4));
      v = fmaxf(v, __shfl_xor(v, 8));
      float mn = fmaxf(mrun[r], v);
      al[r] = __expf(mrun[r] - mn);
      mrun[r] = mn;
      Zp[r] *= al[r]; Tp[r] *= al[r];
    }
#pragma unroll
    for (int dm = 0; dm < 4; dm++) {
      ffrag o = oacc[dm];
      o[0] *= al[0]; o[1] *= al[1]; o[2] *= al[2]; o[3] *= al[3];
      oacc[dm] = o;
    }
    // --- P = exp(s-m), masked; write P^T to LDS (swizzled) ---
    int j0 = t * 64;
#pragma unroll
    for (int jm = 0; jm < 4; jm++) {
      int jcol = jm * 16 + lm;
#pragma unroll
      for (int r = 0; r < 4; r++) {
        int irow = i0 + 4 * lg + r;
        float p = __expf(s[jm][r] - mrun[r]);
        float mv = bf2f(Mb[(size_t)irow * NP + j0 + jcol]);
        float pm = p * mv;
        Zp[r] += p; Tp[r] += pm;
        int prow = 4 * lg + r;
        Pl[prow * 64 + (jcol ^ ((prow & 7) << 3))] = f2bf(pm);
      }
    }
    // --- PV ---
#pragma unroll
    for (int ks = 0; ks < 2; ks++) {
      bfrag pa = LP[lm * 8 + ((ks * 4 + lg) ^ (lm & 7))];
#pragma unroll
      for (int dm = 0; dm < 4; dm++) {
        int vrow = dm * 16 + lm;
        bfrag vb = LV[vrow * 8 + ((ks * 4 + lg) ^ (vrow & 7))];
        oacc[dm] = MFMA16(pa, vb, oacc[dm]);
      }
    }
  }
  // --- finalize: reduce Z,T across the 16 j-lanes, normalize, store ---
#pragma unroll
  for (int r = 0; r < 4; r++) {
    float z = Zp[r], tt = Tp[r];
    z += __shfl_xor(z, 1); z += __shfl_xor(z, 2); z += __shfl_xor(z, 4); z += __shfl_xor(z, 8);
    tt += __shfl_xor(tt, 1); tt += __shfl_xor(tt, 2); tt += __shfl_xor(tt, 4); tt += __shfl_xor(tt, 8);
    Zp[r] = z; Tp[r] = tt;
  }
  float dn[4];
#pragma unroll
  for (int r = 0; r < 4; r++) dn[r] = 1.f / (Tp[r] + EPSI * Zp[r]);
#pragma unroll
  for (int dm = 0; dm < 4; dm++)
#pragma unroll
    for (int r = 0; r < 4; r++) {
      int i = i0 + 4 * lg + r;
      if (i < Nn) Og[((size_t)(b * Nn + i)) * Dd + h * 64 + dm * 16 + lm] = f2bf(oacc[dm][r] * dn[r]);
    }
}

// ---------------- launch ----------------
extern "C" void kernel_launch(void* const* d_in, const int* in_sizes, int n_in,
                              void* d_out, int out_size, void* d_ws, size_t ws_size,
                              hipStream_t stream) {
  const float* x      = (const float*)d_in[0];
  const float* graph  = (const float*)d_in[1];
  const float* transf = (const float*)d_in[2];
  const float* Wqkv   = (const float*)d_in[3];
  const float* bqkv   = (const float*)d_in[4];
  const float* Wproj  = (const float*)d_in[5];
  const float* bproj  = (const float*)d_in[6];
  float* out = (float*)d_out;
  char* ws = (char*)d_ws;

  // ws layout (bytes); total ~76.4 MB. attn_out aliases x_bf16 (disjoint lifetimes).
  unsigned short* xbf  = (unsigned short*)(ws + 0);                 // 12,595,200 (also attn_out)
  unsigned short* wqb  = (unsigned short*)(ws + 12595200);          //  3,538,944
  unsigned short* wpb  = (unsigned short*)(ws + 16134144);          //  1,179,648
  unsigned short* Qb   = (unsigned short*)(ws + 17313792);          // 13,369,344
  unsigned short* Kb   = (unsigned short*)(ws + 30683136);          // 13,369,344
  unsigned short* Vb   = (unsigned short*)(ws + 44052480);          // 13,369,344
  float*          pw   = (float*)(ws + 57421824);                   //     32,768
  unsigned short* mask = (unsigned short*)(ws + 57454592);          // 18,939,904
  unsigned short* aob  = xbf;  // attention output bf16 [8200][768]

  conv_kernel<<<2048, 256, 0, stream>>>(x, xbf, (MROWS * Dd) / 4);
  conv_kernel<<<1728, 256, 0, stream>>>(Wqkv, wqb, (3 * Dd * Dd) / 4);
  conv_kernel<<<576, 256, 0, stream>>>(Wproj, wpb, (Dd * Dd) / 4);
  pw_kernel<<<Bq, 256, 0, stream>>>(transf, pw);
  mask_kernel<<<dim3(NP, Bq), 256, 0, stream>>>(graph, pw, mask);
  padzero_kernel<<<96, 256, 0, stream>>>(Qb, Kb, Vb);
  qkv_gemm_kernel<<<dim3(65, 18), 256, 0, stream>>>(xbf, wqb, bqkv, Qb, Kb, Vb);
  attn_kernel<<<dim3(17, Hh, Bq), 256, 0, stream>>>(Qb, Kb, Vb, mask, aob);
  proj_gemm_kernel<<<dim3(65, 6), 256, 0, stream>>>(aob, wpb, bproj, out);
}

// Round 2
// 271.732 us; speedup vs baseline: 1.4776x; 1.4776x over previous
//
#include <hip/hip_runtime.h>
#include <stdint.h>

// ---------------- constants ----------------
constexpr int Bq = 8, Nn = 1025, Dd = 768, Hh = 12, HDd = 64, Pp = 1024;
constexpr int NP = 1088;              // padded N = 17*64
constexpr int MROWS = Bq * Nn;        // 8200
constexpr float EPSI = 1e-6f;

typedef __attribute__((ext_vector_type(8))) short bfrag;   // 8 bf16 = 4 VGPR
typedef __attribute__((ext_vector_type(4))) float ffrag;   // 4 f32
typedef __attribute__((ext_vector_type(4))) float f4;
typedef __attribute__((ext_vector_type(4))) unsigned short us4;

#define MFMA16(a, b, c) __builtin_amdgcn_mfma_f32_16x16x32_bf16((a), (b), (c), 0, 0, 0)

__device__ __forceinline__ unsigned short f2bf(float f) {
  union { float f; uint32_t u; } v{f};
  uint32_t u = v.u;
  return (unsigned short)((u + 0x7fffu + ((u >> 16) & 1u)) >> 16);  // RNE
}
__device__ __forceinline__ float bf2f(unsigned short s) {
  union { uint32_t u; float f; } v; v.u = ((uint32_t)s) << 16; return v.f;
}

// async global -> LDS, 16B per lane. LDS dest must be wave-uniform base + lane*16.
__device__ __forceinline__ void gload16(const void* g, void* l) {
  __builtin_amdgcn_global_load_lds((const __attribute__((address_space(1))) unsigned int*)g,
                                   (__attribute__((address_space(3))) unsigned int*)l, 16, 0, 0);
}

// ---------------- fp32 -> bf16 conversion ----------------
__global__ __launch_bounds__(256) void conv_kernel(const float* __restrict__ src,
                                                   unsigned short* __restrict__ dst, int n4) {
  int idx = blockIdx.x * blockDim.x + threadIdx.x;
  int stride = gridDim.x * blockDim.x;
  for (int i = idx; i < n4; i += stride) {
    f4 v = ((const f4*)src)[i];
    us4 o; o[0] = f2bf(v[0]); o[1] = f2bf(v[1]); o[2] = f2bf(v[2]); o[3] = f2bf(v[3]);
    ((us4*)dst)[i] = o;
  }
}

// ---------------- pw = t / (sum(t)+eps) ----------------
__global__ __launch_bounds__(256) void pw_kernel(const float* __restrict__ tr, float* __restrict__ pw) {
  int b = blockIdx.x;
  __shared__ float red[256];
  float s = 0.f;
  for (int j = threadIdx.x; j < Pp; j += 256) s += tr[b * Pp + j];
  red[threadIdx.x] = s; __syncthreads();
  for (int o = 128; o > 0; o >>= 1) { if (threadIdx.x < o) red[threadIdx.x] += red[threadIdx.x + o]; __syncthreads(); }
  float inv = 1.f / (red[0] + EPSI);
  for (int j = threadIdx.x; j < Pp; j += 256) pw[b * Pp + j] = tr[b * Pp + j] * inv;
}

// ---------------- mask bf16 [B][NP][NP], zero padded ----------------
__global__ __launch_bounds__(256) void mask_kernel(const float* __restrict__ graph,
                                                   const float* __restrict__ pw,
                                                   unsigned short* __restrict__ mask) {
  int i = blockIdx.x, b = blockIdx.y;
  unsigned short* mrow = mask + ((size_t)b * NP + i) * NP;
  if (i >= Nn) { for (int j = threadIdx.x; j < NP; j += 256) mrow[j] = 0; return; }
  if (i == 0) {
    for (int j = threadIdx.x; j < NP; j += 256) {
      float v = (j == 0) ? 1.f : (j <= Pp ? pw[b * Pp + j - 1] : 0.f);
      mrow[j] = f2bf(v);
    }
  } else {
    const float* grow = graph + ((size_t)b * Pp + (i - 1)) * Pp;
    for (int j = threadIdx.x; j < NP; j += 256) {
      float v = (j == 0) ? pw[b * Pp + i - 1] : (j <= Pp ? grow[j - 1] : 0.f);
      mrow[j] = f2bf(v);
    }
  }
}

// ---------------- zero pad rows of Q/K and pad cols of VT ----------------
__global__ __launch_bounds__(256) void padzero_kernel(unsigned short* __restrict__ Qo,
                                                      unsigned short* __restrict__ Ko,
                                                      unsigned short* __restrict__ Vo) {
  int bh = blockIdx.x;  // 0..95
  unsigned short* qp = Qo + ((size_t)bh * NP + Nn) * 64;
  unsigned short* kp = Ko + ((size_t)bh * NP + Nn) * 64;
  for (int idx = threadIdx.x; idx < (NP - Nn) * 64; idx += 256) { qp[idx] = 0; kp[idx] = 0; }
  unsigned short* vp = Vo + (size_t)bh * 64 * NP;
  for (int idx = threadIdx.x; idx < 64 * (NP - Nn); idx += 256) {
    int d = idx / (NP - Nn), j = Nn + (idx - d * (NP - Nn));
    vp[(size_t)d * NP + j] = 0;
  }
}

// ---------------- GEMM core: 128x128 tile, BK=64, K=768, bf16 MFMA ----------------
// m97 structure: global_load_lds (16B) staging, 2 barriers per K-step.
// LDS: A tile [128 rows][8 chunk-slots] uint4; slot p of row r holds global chunk p^(r&7)
// (achieved by pre-swizzling the per-lane GLOBAL address; LDS dest stays linear = tid+256q).
__device__ __forceinline__ void gemm_main(const unsigned short* __restrict__ A, int rowA0, int rowAmax,
                                          const unsigned short* __restrict__ Bw, int rowB0,
                                          uint4* lds, ffrag acc[4][4], int tid) {
  const int l = tid & 63, lm = l & 15, lg = l >> 4, w = tid >> 6, wr = w >> 1, wc = w & 1;
  const unsigned short* aS[4]; const unsigned short* bS[4];
#pragma unroll
  for (int q = 0; q < 4; q++) {
    int c = tid + 256 * q, r = c >> 3, p = c & 7, g = p ^ (r & 7);
    int ra = rowA0 + r; if (ra > rowAmax) ra = rowAmax;
    aS[q] = A + (size_t)ra * 768 + 8 * g;
    bS[q] = Bw + (size_t)(rowB0 + r) * 768 + 8 * g;
  }
  uint4* ldsA = lds;
  uint4* ldsB = lds + 1024;
#pragma unroll 1
  for (int kt = 0; kt < 12; kt++) {
    __syncthreads();  // previous K-step's reads done; safe to overwrite LDS
#pragma unroll
    for (int q = 0; q < 4; q++) {
      gload16(aS[q], ldsA + tid + 256 * q); aS[q] += 64;
      gload16(bS[q], ldsB + tid + 256 * q); bS[q] += 64;
    }
    __syncthreads();  // drains vmcnt -> tile resident
    const bfrag* LA = (const bfrag*)lds;
    const bfrag* LB = (const bfrag*)(lds + 1024);
    bfrag af[4][2], bf_[4][2];
#pragma unroll
    for (int am = 0; am < 4; am++) {
      int row = wr * 64 + am * 16 + lm;
      af[am][0] = LA[row * 8 + ((0 + lg) ^ (row & 7))];
      af[am][1] = LA[row * 8 + ((4 + lg) ^ (row & 7))];
    }
#pragma unroll
    for (int an = 0; an < 4; an++) {
      int row = wc * 64 + an * 16 + lm;
      bf_[an][0] = LB[row * 8 + ((0 + lg) ^ (row & 7))];
      bf_[an][1] = LB[row * 8 + ((4 + lg) ^ (row & 7))];
    }
#pragma unroll
    for (int am = 0; am < 4; am++)
#pragma unroll
      for (int an = 0; an < 4; an++) {
        acc[am][an] = MFMA16(af[am][0], bf_[an][0], acc[am][an]);
        acc[am][an] = MFMA16(af[am][1], bf_[an][1], acc[am][an]);
      }
  }
}

// ---------------- kernel 1: QKV GEMM + scatter epilogue ----------------
__global__ __launch_bounds__(256) void qkv_gemm_kernel(const unsigned short* __restrict__ X,
                                                       const unsigned short* __restrict__ W,
                                                       const float* __restrict__ bias,
                                                       unsigned short* __restrict__ Qo,
                                                       unsigned short* __restrict__ Ko,
                                                       unsigned short* __restrict__ Vo) {
  __shared__ uint4 lds[2048];
  int tid = threadIdx.x;
  ffrag zero4 = {0.f, 0.f, 0.f, 0.f};
  ffrag acc[4][4];
#pragma unroll
  for (int i = 0; i < 4; i++)
#pragma unroll
    for (int j = 0; j < 4; j++) acc[i][j] = zero4;
  gemm_main(X, blockIdx.x * 128, MROWS - 1, W, blockIdx.y * 128, lds, acc, tid);
  const int l = tid & 63, lm = l & 15, lg = l >> 4, w = tid >> 6, wr = w >> 1, wc = w & 1;
#pragma unroll
  for (int an = 0; an < 4; an++) {
    int gc = blockIdx.y * 128 + wc * 64 + an * 16 + lm;
    int which = gc / 768, rr = gc - which * 768, h = rr >> 6, hd = rr & 63;
    float bv = bias[gc];
#pragma unroll
    for (int am = 0; am < 4; am++) {
      int grb = blockIdx.x * 128 + wr * 64 + am * 16 + 4 * lg;
#pragma unroll
      for (int r = 0; r < 4; r++) {
        int gr = grb + r;
        if (gr >= MROWS) continue;
        int b = gr / Nn, i = gr - b * Nn;
        size_t bh = (size_t)(b * Hh + h);
        float v = acc[am][an][r] + bv;
        if (which == 0)      Qo[(bh * NP + i) * 64 + hd] = f2bf(v * 0.125f);  // fold HD^-0.5
        else if (which == 1) Ko[(bh * NP + i) * 64 + hd] = f2bf(v);
        else                 Vo[(bh * 64 + hd) * NP + i] = f2bf(v);           // V transposed
      }
    }
  }
}

// ---------------- kernel 3: proj GEMM + bias -> fp32 out ----------------
__global__ __launch_bounds__(256) void proj_gemm_kernel(const unsigned short* __restrict__ A,
                                                        const unsigned short* __restrict__ W,
                                                        const float* __restrict__ bias,
                                                        float* __restrict__ out) {
  __shared__ uint4 lds[2048];
  int tid = threadIdx.x;
  ffrag zero4 = {0.f, 0.f, 0.f, 0.f};
  ffrag acc[4][4];
#pragma unroll
  for (int i = 0; i < 4; i++)
#pragma unroll
    for (int j = 0; j < 4; j++) acc[i][j] = zero4;
  gemm_main(A, blockIdx.x * 128, MROWS - 1, W, blockIdx.y * 128, lds, acc, tid);
  const int l = tid & 63, lm = l & 15, lg = l >> 4, w = tid >> 6, wr = w >> 1, wc = w & 1;
#pragma unroll
  for (int an = 0; an < 4; an++) {
    int gc = blockIdx.y * 128 + wc * 64 + an * 16 + lm;
    float bv = bias[gc];
#pragma unroll
    for (int am = 0; am < 4; am++) {
      int grb = blockIdx.x * 128 + wr * 64 + am * 16 + 4 * lg;
#pragma unroll
      for (int r = 0; r < 4; r++) {
        int gr = grb + r;
        if (gr >= MROWS) continue;
        out[(size_t)gr * 768 + gc] = acc[am][an][r] + bv;
      }
    }
  }
}

// ---------------- kernel 2: fused masked attention (flash-style) ----------------
// block: 4 waves x 16 q-rows = 64 rows. KV tiles of 64. Q pre-scaled.
// out = O / (T + eps*Z) with O=sum e^{s-m}*mask*v, T=sum e^{s-m}*mask, Z=sum e^{s-m}.
__global__ __launch_bounds__(256) void attn_kernel(const unsigned short* __restrict__ Qg,
                                                   const unsigned short* __restrict__ Kg,
                                                   const unsigned short* __restrict__ Vg,
                                                   const unsigned short* __restrict__ Mg,
                                                   unsigned short* __restrict__ Og) {
  __shared__ uint4 smem[1536];  // K 8KB | V 8KB | P 4x2KB
  int tid = threadIdx.x, w = tid >> 6, l = tid & 63, lm = l & 15, lg = l >> 4;
  int ib = blockIdx.x, h = blockIdx.y, b = blockIdx.z;
  size_t bh = (size_t)(b * Hh + h);
  const unsigned short* Qb = Qg + bh * NP * 64;
  const unsigned short* Kb = Kg + bh * NP * 64;
  const unsigned short* Vb = Vg + bh * 64 * NP;
  const unsigned short* Mb = Mg + (size_t)b * NP * NP;
  int i0 = ib * 64 + w * 16;

  bfrag qf0 = *(const bfrag*)(Qb + (size_t)(i0 + lm) * 64 + 8 * lg);
  bfrag qf1 = *(const bfrag*)(Qb + (size_t)(i0 + lm) * 64 + 32 + 8 * lg);

  ffrag zero4 = {0.f, 0.f, 0.f, 0.f};
  ffrag oacc[4] = {zero4, zero4, zero4, zero4};
  float mrun[4] = {-1e30f, -1e30f, -1e30f, -1e30f};
  float Zp[4] = {0.f, 0.f, 0.f, 0.f}, Tp[4] = {0.f, 0.f, 0.f, 0.f};

  int rS = tid >> 3, pS = tid & 7, gS = pS ^ (rS & 7);
  const unsigned short* kS = Kb + rS * 64 + 8 * gS;
  const unsigned short* vS = Vb + (size_t)rS * NP + 8 * gS;
  uint4* ldsK4 = smem; uint4* ldsV4 = smem + 512;
  unsigned short* Pl = (unsigned short*)(smem + 1024 + w * 128);
  const bfrag* LK = (const bfrag*)ldsK4;
  const bfrag* LV = (const bfrag*)ldsV4;
  const bfrag* LP = (const bfrag*)Pl;

#pragma unroll 1
  for (int t = 0; t < 17; t++) {
    uint4 k0 = *(const uint4*)kS, k1 = *(const uint4*)(kS + 2048);
    uint4 v0 = *(const uint4*)vS, v1 = *(const uint4*)(vS + 32 * NP);
    __syncthreads();
    ldsK4[tid] = k0; ldsK4[tid + 256] = k1; ldsV4[tid] = v0; ldsV4[tid + 256] = v1;
    __syncthreads();
    kS += 64 * 64; vS += 64;

    // --- QK^T ---
    ffrag s[4];
#pragma unroll
    for (int jm = 0; jm < 4; jm++) {
      int row = jm * 16 + lm;
      bfrag b0 = LK[row * 8 + ((0 + lg) ^ (row & 7))];
      bfrag b1 = LK[row * 8 + ((4 + lg) ^ (row & 7))];
      ffrag a = zero4;
      a = MFMA16(qf0, b0, a);
      a = MFMA16(qf1, b1, a);
      s[jm] = a;
    }
    // --- online softmax bookkeeping ---
    float al[4];
#pragma unroll
    for (int r = 0; r < 4; r++) {
      float v = fmaxf(fmaxf(s[0][r], s[1][r]), fmaxf(s[2][r], s[3][r]));
      v = fmaxf(v, __shfl_xor(v, 1));
      v = fmaxf(v, __shfl_xor(v, 2));
      v = fmaxf(v, __shfl_xor(v, 4));
      v = fmaxf(v, __shfl_xor(v, 8));
      float mn = fmaxf(mrun[r], v);
      al[r] = __expf(mrun[r] - mn);
      mrun[r] = mn;
      Zp[r] *= al[r]; Tp[r] *= al[r];
    }
#pragma unroll
    for (int dm = 0; dm < 4; dm++) {
      ffrag o = oacc[dm];
      o[0] *= al[0]; o[1] *= al[1]; o[2] *= al[2]; o[3] *= al[3];
      oacc[dm] = o;
    }
    // --- P = exp(s-m), masked; write P^T to LDS (swizzled) ---
    int j0 = t * 64;
#pragma unroll
    for (int jm = 0; jm < 4; jm++) {
      int jcol = jm * 16 + lm;
#pragma unroll
      for (int r = 0; r < 4; r++) {
        int irow = i0 + 4 * lg + r;
        float p = __expf(s[jm][r] - mrun[r]);
        float mv = bf2f(Mb[(size_t)irow * NP + j0 + jcol]);
        float pm = p * mv;
        Zp[r] += p; Tp[r] += pm;
        int prow = 4 * lg + r;
        Pl[prow * 64 + (jcol ^ ((prow & 7) << 3))] = f2bf(pm);
      }
    }
    // --- PV ---
#pragma unroll
    for (int ks = 0; ks < 2; ks++) {
      bfrag pa = LP[lm * 8 + ((ks * 4 + lg) ^ (lm & 7))];
#pragma unroll
      for (int dm = 0; dm < 4; dm++) {
        int vrow = dm * 16 + lm;
        bfrag vb = LV[vrow * 8 + ((ks * 4 + lg) ^ (vrow & 7))];
        oacc[dm] = MFMA16(pa, vb, oacc[dm]);
      }
    }
  }
  // --- finalize: reduce Z,T across the 16 j-lanes, normalize, store ---
#pragma unroll
  for (int r = 0; r < 4; r++) {
    float z = Zp[r], tt = Tp[r];
    z += __shfl_xor(z, 1); z += __shfl_xor(z, 2); z += __shfl_xor(z, 4); z += __shfl_xor(z, 8);
    tt += __shfl_xor(tt, 1); tt += __shfl_xor(tt, 2); tt += __shfl_xor(tt, 4); tt += __shfl_xor(tt, 8);
    Zp[r] = z; Tp[r] = tt;
  }
  float dn[4];
#pragma unroll
  for (int r = 0; r < 4; r++) dn[r] = 1.f / (Tp[r] + EPSI * Zp[r]);
#pragma unroll
  for (int dm = 0; dm < 4; dm++)
#pragma unroll
    for (int r = 0; r < 4; r++) {
      int i = i0 + 4 * lg + r;
      if (i < Nn) Og[((size_t)(b * Nn + i)) * Dd + h * 64 + dm * 16 + lm] = f2bf(oacc[dm][r] * dn[r]);
    }
}

// ---------------- launch ----------------
extern "C" void kernel_launch(void* const* d_in, const int* in_sizes, int n_in,
                              void* d_out, int out_size, void* d_ws, size_t ws_size,
                              hipStream_t stream) {
  const float* x      = (const float*)d_in[0];
  const float* graph  = (const float*)d_in[1];
  const float* transf = (const float*)d_in[2];
  const float* Wqkv   = (const float*)d_in[3];
  const float* bqkv   = (const float*)d_in[4];
  const float* Wproj  = (const float*)d_in[5];
  const float* bproj  = (const float*)d_in[6];
  float* out = (float*)d_out;
  char* ws = (char*)d_ws;

  // ws layout (bytes); total ~76.4 MB. attn_out aliases x_bf16 (disjoint lifetimes).
  unsigned short* xbf  = (unsigned short*)(ws + 0);                 // 12,595,200 (also attn_out)
  unsigned short* wqb  = (unsigned short*)(ws + 12595200);          //  3,538,944
  unsigned short* wpb  = (unsigned short*)(ws + 16134144);          //  1,179,648
  unsigned short* Qb   = (unsigned short*)(ws + 17313792);          // 13,369,344
  unsigned short* Kb   = (unsigned short*)(ws + 30683136);          // 13,369,344
  unsigned short* Vb   = (unsigned short*)(ws + 44052480);          // 13,369,344
  float*          pw   = (float*)(ws + 57421824);                   //     32,768
  unsigned short* mask = (unsigned short*)(ws + 57454592);          // 18,939,904
  unsigned short* aob  = xbf;  // attention output bf16 [8200][768]

  conv_kernel<<<2048, 256, 0, stream>>>(x, xbf, (MROWS * Dd) / 4);
  conv_kernel<<<1728, 256, 0, stream>>>(Wqkv, wqb, (3 * Dd * Dd) / 4);
  conv_kernel<<<576, 256, 0, stream>>>(Wproj, wpb, (Dd * Dd) / 4);
  pw_kernel<<<Bq, 256, 0, stream>>>(transf, pw);
  mask_kernel<<<dim3(NP, Bq), 256, 0, stream>>>(graph, pw, mask);
  padzero_kernel<<<96, 256, 0, stream>>>(Qb, Kb, Vb);
  qkv_gemm_kernel<<<dim3(65, 18), 256, 0, stream>>>(xbf, wqb, bqkv, Qb, Kb, Vb);
  attn_kernel<<<dim3(17, Hh, Bq), 256, 0, stream>>>(Qb, Kb, Vb, mask, aob);
  proj_gemm_kernel<<<dim3(65, 6), 256, 0, stream>>>(aob, wpb, bproj, out);
}

// Round 3
// 227.522 us; speedup vs baseline: 1.7647x; 1.1943x over previous
//
#include <hip/hip_runtime.h>
#include <stdint.h>

// ---------------- constants ----------------
constexpr int Bq = 8, Nn = 1025, Dd = 768, Hh = 12, HDd = 64, Pp = 1024;
constexpr int NP = 1088;              // padded N = 17*64
constexpr int MROWS = Bq * Nn;        // 8200
constexpr float EPSI = 1e-6f;

typedef __attribute__((ext_vector_type(8))) short bfrag;   // 8 bf16 = 4 VGPR
typedef __attribute__((ext_vector_type(4))) float ffrag;   // 4 f32
typedef __attribute__((ext_vector_type(4))) float f4;
typedef __attribute__((ext_vector_type(4))) unsigned short us4;

#define MFMA16(a, b, c) __builtin_amdgcn_mfma_f32_16x16x32_bf16((a), (b), (c), 0, 0, 0)

#if __has_builtin(__builtin_amdgcn_exp2f)
#define EXP2(x) __builtin_amdgcn_exp2f(x)
#else
#define EXP2(x) exp2f(x)
#endif

__device__ __forceinline__ unsigned short f2bf(float f) {
  union { float f; uint32_t u; } v{f};
  uint32_t u = v.u;
  return (unsigned short)((u + 0x7fffu + ((u >> 16) & 1u)) >> 16);  // RNE
}
__device__ __forceinline__ float bf2f(unsigned short s) {
  union { uint32_t u; float f; } v; v.u = ((uint32_t)s) << 16; return v.f;
}
// pack 2 f32 -> 2 bf16 in one u32 (lo = a, hi = b), RNE
__device__ __forceinline__ uint32_t pkbf(float a, float b) {
  uint32_t r;
  asm("v_cvt_pk_bf16_f32 %0, %1, %2" : "=v"(r) : "v"(a), "v"(b));
  return r;
}

// async global -> LDS, 16B per lane. LDS dest must be wave-uniform base + lane*16.
__device__ __forceinline__ void gload16(const void* g, void* l) {
  __builtin_amdgcn_global_load_lds((const __attribute__((address_space(1))) unsigned int*)g,
                                   (__attribute__((address_space(3))) unsigned int*)l, 16, 0, 0);
}

// ---------------- fp32 -> bf16 conversion ----------------
__global__ __launch_bounds__(256) void conv_kernel(const float* __restrict__ src,
                                                   unsigned short* __restrict__ dst, int n4) {
  int idx = blockIdx.x * blockDim.x + threadIdx.x;
  int stride = gridDim.x * blockDim.x;
  for (int i = idx; i < n4; i += stride) {
    f4 v = ((const f4*)src)[i];
    us4 o; o[0] = f2bf(v[0]); o[1] = f2bf(v[1]); o[2] = f2bf(v[2]); o[3] = f2bf(v[3]);
    ((us4*)dst)[i] = o;
  }
}

// ---------------- pw = t / (sum(t)+eps) ----------------
__global__ __launch_bounds__(256) void pw_kernel(const float* __restrict__ tr, float* __restrict__ pw) {
  int b = blockIdx.x;
  __shared__ float red[256];
  float s = 0.f;
  for (int j = threadIdx.x; j < Pp; j += 256) s += tr[b * Pp + j];
  red[threadIdx.x] = s; __syncthreads();
  for (int o = 128; o > 0; o >>= 1) { if (threadIdx.x < o) red[threadIdx.x] += red[threadIdx.x + o]; __syncthreads(); }
  float inv = 1.f / (red[0] + EPSI);
  for (int j = threadIdx.x; j < Pp; j += 256) pw[b * Pp + j] = tr[b * Pp + j] * inv;
}

// ---------------- mask bf16 [B][NP][NP], zero padded ----------------
__global__ __launch_bounds__(256) void mask_kernel(const float* __restrict__ graph,
                                                   const float* __restrict__ pw,
                                                   unsigned short* __restrict__ mask) {
  int i = blockIdx.x, b = blockIdx.y;
  unsigned short* mrow = mask + ((size_t)b * NP + i) * NP;
  if (i >= Nn) { for (int j = threadIdx.x; j < NP; j += 256) mrow[j] = 0; return; }
  if (i == 0) {
    for (int j = threadIdx.x; j < NP; j += 256) {
      float v = (j == 0) ? 1.f : (j <= Pp ? pw[b * Pp + j - 1] : 0.f);
      mrow[j] = f2bf(v);
    }
  } else {
    const float* grow = graph + ((size_t)b * Pp + (i - 1)) * Pp;
    for (int j = threadIdx.x; j < NP; j += 256) {
      float v = (j == 0) ? pw[b * Pp + i - 1] : (j <= Pp ? grow[j - 1] : 0.f);
      mrow[j] = f2bf(v);
    }
  }
}

// ---------------- zero pad rows of Q/K and pad cols of VT ----------------
__global__ __launch_bounds__(256) void padzero_kernel(unsigned short* __restrict__ Qo,
                                                      unsigned short* __restrict__ Ko,
                                                      unsigned short* __restrict__ Vo) {
  int bh = blockIdx.x;  // 0..95
  unsigned short* qp = Qo + ((size_t)bh * NP + Nn) * 64;
  unsigned short* kp = Ko + ((size_t)bh * NP + Nn) * 64;
  for (int idx = threadIdx.x; idx < (NP - Nn) * 64; idx += 256) { qp[idx] = 0; kp[idx] = 0; }
  unsigned short* vp = Vo + (size_t)bh * 64 * NP;
  for (int idx = threadIdx.x; idx < 64 * (NP - Nn); idx += 256) {
    int d = idx / (NP - Nn), j = Nn + (idx - d * (NP - Nn));
    vp[(size_t)d * NP + j] = 0;
  }
}

// ---------------- GEMM core: 128x128 tile, BK=64, K=768, bf16 MFMA ----------------
// m97 structure: global_load_lds (16B) staging, 2 barriers per K-step.
// LDS: A tile [128 rows][8 chunk-slots] uint4; slot p of row r holds global chunk p^(r&7)
// (achieved by pre-swizzling the per-lane GLOBAL address; LDS dest stays linear = tid+256q).
__device__ __forceinline__ void gemm_main(const unsigned short* __restrict__ A, int rowA0, int rowAmax,
                                          const unsigned short* __restrict__ Bw, int rowB0,
                                          uint4* lds, ffrag acc[4][4], int tid) {
  const int l = tid & 63, lm = l & 15, lg = l >> 4, w = tid >> 6, wr = w >> 1, wc = w & 1;
  const unsigned short* aS[4]; const unsigned short* bS[4];
#pragma unroll
  for (int q = 0; q < 4; q++) {
    int c = tid + 256 * q, r = c >> 3, p = c & 7, g = p ^ (r & 7);
    int ra = rowA0 + r; if (ra > rowAmax) ra = rowAmax;
    aS[q] = A + (size_t)ra * 768 + 8 * g;
    bS[q] = Bw + (size_t)(rowB0 + r) * 768 + 8 * g;
  }
  uint4* ldsA = lds;
  uint4* ldsB = lds + 1024;
#pragma unroll 1
  for (int kt = 0; kt < 12; kt++) {
    __syncthreads();  // previous K-step's reads done; safe to overwrite LDS
#pragma unroll
    for (int q = 0; q < 4; q++) {
      gload16(aS[q], ldsA + tid + 256 * q); aS[q] += 64;
      gload16(bS[q], ldsB + tid + 256 * q); bS[q] += 64;
    }
    __syncthreads();  // drains vmcnt -> tile resident
    const bfrag* LA = (const bfrag*)lds;
    const bfrag* LB = (const bfrag*)(lds + 1024);
    bfrag af[4][2], bf_[4][2];
#pragma unroll
    for (int am = 0; am < 4; am++) {
      int row = wr * 64 + am * 16 + lm;
      af[am][0] = LA[row * 8 + ((0 + lg) ^ (row & 7))];
      af[am][1] = LA[row * 8 + ((4 + lg) ^ (row & 7))];
    }
#pragma unroll
    for (int an = 0; an < 4; an++) {
      int row = wc * 64 + an * 16 + lm;
      bf_[an][0] = LB[row * 8 + ((0 + lg) ^ (row & 7))];
      bf_[an][1] = LB[row * 8 + ((4 + lg) ^ (row & 7))];
    }
#pragma unroll
    for (int am = 0; am < 4; am++)
#pragma unroll
      for (int an = 0; an < 4; an++) {
        acc[am][an] = MFMA16(af[am][0], bf_[an][0], acc[am][an]);
        acc[am][an] = MFMA16(af[am][1], bf_[an][1], acc[am][an]);
      }
  }
}

// ---------------- kernel 1: QKV GEMM + scatter epilogue ----------------
__global__ __launch_bounds__(256) void qkv_gemm_kernel(const unsigned short* __restrict__ X,
                                                       const unsigned short* __restrict__ W,
                                                       const float* __restrict__ bias,
                                                       unsigned short* __restrict__ Qo,
                                                       unsigned short* __restrict__ Ko,
                                                       unsigned short* __restrict__ Vo) {
  __shared__ uint4 lds[2048];
  int tid = threadIdx.x;
  ffrag zero4 = {0.f, 0.f, 0.f, 0.f};
  ffrag acc[4][4];
#pragma unroll
  for (int i = 0; i < 4; i++)
#pragma unroll
    for (int j = 0; j < 4; j++) acc[i][j] = zero4;
  gemm_main(X, blockIdx.x * 128, MROWS - 1, W, blockIdx.y * 128, lds, acc, tid);
  const int l = tid & 63, lm = l & 15, lg = l >> 4, w = tid >> 6, wr = w >> 1, wc = w & 1;
#pragma unroll
  for (int an = 0; an < 4; an++) {
    int gc = blockIdx.y * 128 + wc * 64 + an * 16 + lm;
    int which = gc / 768, rr = gc - which * 768, h = rr >> 6, hd = rr & 63;
    float bv = bias[gc];
#pragma unroll
    for (int am = 0; am < 4; am++) {
      int grb = blockIdx.x * 128 + wr * 64 + am * 16 + 4 * lg;
#pragma unroll
      for (int r = 0; r < 4; r++) {
        int gr = grb + r;
        if (gr >= MROWS) continue;
        int b = gr / Nn, i = gr - b * Nn;
        size_t bh = (size_t)(b * Hh + h);
        float v = acc[am][an][r] + bv;
        // Q prescale folds softmax scale AND log2(e) for exp2-domain softmax:
        // 0.125 * 1.44269504 = 0.18033688
        if (which == 0)      Qo[(bh * NP + i) * 64 + hd] = f2bf(v * 0.18033688f);
        else if (which == 1) Ko[(bh * NP + i) * 64 + hd] = f2bf(v);
        else                 Vo[(bh * 64 + hd) * NP + i] = f2bf(v);           // V transposed
      }
    }
  }
}

// ---------------- kernel 3: proj GEMM + bias -> fp32 out ----------------
__global__ __launch_bounds__(256) void proj_gemm_kernel(const unsigned short* __restrict__ A,
                                                        const unsigned short* __restrict__ W,
                                                        const float* __restrict__ bias,
                                                        float* __restrict__ out) {
  __shared__ uint4 lds[2048];
  int tid = threadIdx.x;
  ffrag zero4 = {0.f, 0.f, 0.f, 0.f};
  ffrag acc[4][4];
#pragma unroll
  for (int i = 0; i < 4; i++)
#pragma unroll
    for (int j = 0; j < 4; j++) acc[i][j] = zero4;
  gemm_main(A, blockIdx.x * 128, MROWS - 1, W, blockIdx.y * 128, lds, acc, tid);
  const int l = tid & 63, lm = l & 15, lg = l >> 4, w = tid >> 6, wr = w >> 1, wc = w & 1;
#pragma unroll
  for (int an = 0; an < 4; an++) {
    int gc = blockIdx.y * 128 + wc * 64 + an * 16 + lm;
    float bv = bias[gc];
#pragma unroll
    for (int am = 0; am < 4; am++) {
      int grb = blockIdx.x * 128 + wr * 64 + am * 16 + 4 * lg;
#pragma unroll
      for (int r = 0; r < 4; r++) {
        int gr = grb + r;
        if (gr >= MROWS) continue;
        out[(size_t)gr * 768 + gc] = acc[am][an][r] + bv;
      }
    }
  }
}

// ---------------- kernel 2: fused masked attention, swapped-QK^T, no-max softmax ----------------
// Lane owns q-row i = i0 + lm; j-coverage per lane: {16*jm + 4*lg + r}.
// s in exp2 domain (Q pre-scaled by 0.125*log2e). No online max (|s| ~ 0.3 << fp32 range).
// out = (sum e2^s * m * v) / (sum e2^s * m + eps * sum e2^s)  == reference exactly.
__global__ __launch_bounds__(256) void attn_kernel(const unsigned short* __restrict__ Qg,
                                                   const unsigned short* __restrict__ Kg,
                                                   const unsigned short* __restrict__ Vg,
                                                   const unsigned short* __restrict__ Mg,
                                                   unsigned short* __restrict__ Og) {
  __shared__ uint4 smem[1536];  // K 8KB | V 8KB | P 4x2KB
  int tid = threadIdx.x, w = tid >> 6, l = tid & 63, lm = l & 15, lg = l >> 4;
  // XCD swizzle: b = bx & 7 pins batch->XCD (round-robin dispatch); within XCD h varies fastest
  // so the 12 heads sharing a mask row-tile are consecutive on the same L2.
  int bx = blockIdx.x;
  int b = bx & 7, t5 = bx >> 3;
  int h = t5 % 12, ib = t5 / 12;
  size_t bh = (size_t)(b * Hh + h);
  const unsigned short* Qb = Qg + bh * NP * 64;
  const unsigned short* Kb = Kg + bh * NP * 64;
  const unsigned short* Vb = Vg + bh * 64 * NP;
  int i0 = ib * 64 + w * 16;
  int irow = i0 + lm;
  const unsigned short* Mrow = Mg + (size_t)b * NP * NP + (size_t)irow * NP;

  bfrag qf0 = *(const bfrag*)(Qb + (size_t)irow * 64 + 8 * lg);
  bfrag qf1 = *(const bfrag*)(Qb + (size_t)irow * 64 + 32 + 8 * lg);

  ffrag zero4 = {0.f, 0.f, 0.f, 0.f};
  ffrag oacc[4] = {zero4, zero4, zero4, zero4};
  float Zp = 0.f, Tp = 0.f;

  int rS = tid >> 3, pS = tid & 7, gS = pS ^ (rS & 7);
  const unsigned short* kS = Kb + rS * 64 + 8 * gS;
  const unsigned short* vS = Vb + (size_t)rS * NP + 8 * gS;
  uint4* ldsK4 = smem; uint4* ldsV4 = smem + 512;
  char* Pbase = (char*)(smem + 1024) + w * 2048;   // per-wave P tile [16 i][64 j] bf16, chunk-XOR
  const bfrag* LK = (const bfrag*)ldsK4;
  const bfrag* LV = (const bfrag*)ldsV4;

#pragma unroll 1
  for (int t = 0; t < 17; t++) {
    // K/V reg-staged prefetch (issued before barrier -> overlaps prev tile compute)
    uint4 k0 = *(const uint4*)kS, k1 = *(const uint4*)(kS + 2048);
    uint4 v0 = *(const uint4*)vS, v1 = *(const uint4*)(vS + 32 * NP);
    // mask for this tile: 4x 8B vector loads (j = 16*jm + 4*lg + 0..3), issued early
    int j0 = t * 64;
    us4 mv[4];
#pragma unroll
    for (int jm = 0; jm < 4; jm++) mv[jm] = *(const us4*)(Mrow + j0 + 16 * jm + 4 * lg);
    __syncthreads();
    ldsK4[tid] = k0; ldsK4[tid + 256] = k1; ldsV4[tid] = v0; ldsV4[tid + 256] = v1;
    __syncthreads();
    kS += 64 * 64; vS += 64;

    // --- QK^T (swapped): s[jm][r] = S[j0+16jm+4lg+r][i0+lm] ---
    ffrag s[4];
#pragma unroll
    for (int jm = 0; jm < 4; jm++) {
      int row = jm * 16 + lm;
      bfrag a0 = LK[row * 8 + ((0 + lg) ^ (row & 7))];
      bfrag a1 = LK[row * 8 + ((4 + lg) ^ (row & 7))];
      ffrag a = zero4;
      a = MFMA16(a0, qf0, a);
      a = MFMA16(a1, qf1, a);
      s[jm] = a;
    }
    // --- p = exp2(s); pm = p*mask; accumulate Z,T; pack + write P ---
#pragma unroll
    for (int jm = 0; jm < 4; jm++) {
      float p0 = EXP2(s[jm][0]), p1 = EXP2(s[jm][1]), p2 = EXP2(s[jm][2]), p3 = EXP2(s[jm][3]);
      Zp += (p0 + p1) + (p2 + p3);
      float q0 = p0 * bf2f(mv[jm][0]), q1 = p1 * bf2f(mv[jm][1]);
      float q2 = p2 * bf2f(mv[jm][2]), q3 = p3 * bf2f(mv[jm][3]);
      Tp += (q0 + q1) + (q2 + q3);
      uint2 pk; pk.x = pkbf(q0, q1); pk.y = pkbf(q2, q3);
      int cpos = (((jm << 1) | (lg >> 1)) ^ (lm & 7));
      *(uint2*)(Pbase + lm * 128 + cpos * 16 + 8 * (lg & 1)) = pk;
    }
    // --- PV: A = P[16i][64j] (chunk-XOR read), B = V^T rows from LDS ---
#pragma unroll
    for (int ks = 0; ks < 2; ks++) {
      bfrag pa = *(const bfrag*)(Pbase + lm * 128 + ((((ks << 2) | lg)) ^ (lm & 7)) * 16);
#pragma unroll
      for (int dm = 0; dm < 4; dm++) {
        int vrow = dm * 16 + lm;
        bfrag vb = LV[vrow * 8 + ((ks * 4 + lg) ^ (vrow & 7))];
        oacc[dm] = MFMA16(pa, vb, oacc[dm]);
      }
    }
  }
  // --- finalize: reduce Z,T across lg lanes; broadcast per-row denominators ---
  Zp += __shfl_xor(Zp, 16); Zp += __shfl_xor(Zp, 32);
  Tp += __shfl_xor(Tp, 16); Tp += __shfl_xor(Tp, 32);
  float dn_row = 1.f / (Tp + EPSI * Zp);   // valid at every lane for row i0 + lm
  float dn[4];
#pragma unroll
  for (int r = 0; r < 4; r++) dn[r] = __shfl(dn_row, 4 * lg + r);  // row of oacc reg r
#pragma unroll
  for (int dm = 0; dm < 4; dm++)
#pragma unroll
    for (int r = 0; r < 4; r++) {
      int i = i0 + 4 * lg + r;
      if (i < Nn) Og[((size_t)(b * Nn + i)) * Dd + h * 64 + dm * 16 + lm] = f2bf(oacc[dm][r] * dn[r]);
    }
}

// ---------------- launch ----------------
extern "C" void kernel_launch(void* const* d_in, const int* in_sizes, int n_in,
                              void* d_out, int out_size, void* d_ws, size_t ws_size,
                              hipStream_t stream) {
  const float* x      = (const float*)d_in[0];
  const float* graph  = (const float*)d_in[1];
  const float* transf = (const float*)d_in[2];
  const float* Wqkv   = (const float*)d_in[3];
  const float* bqkv   = (const float*)d_in[4];
  const float* Wproj  = (const float*)d_in[5];
  const float* bproj  = (const float*)d_in[6];
  float* out = (float*)d_out;
  char* ws = (char*)d_ws;

  // ws layout (bytes); total ~76.4 MB. attn_out aliases x_bf16 (disjoint lifetimes).
  unsigned short* xbf  = (unsigned short*)(ws + 0);                 // 12,595,200 (also attn_out)
  unsigned short* wqb  = (unsigned short*)(ws + 12595200);          //  3,538,944
  unsigned short* wpb  = (unsigned short*)(ws + 16134144);          //  1,179,648
  unsigned short* Qb   = (unsigned short*)(ws + 17313792);          // 13,369,344
  unsigned short* Kb   = (unsigned short*)(ws + 30683136);          // 13,369,344
  unsigned short* Vb   = (unsigned short*)(ws + 44052480);          // 13,369,344
  float*          pw   = (float*)(ws + 57421824);                   //     32,768
  unsigned short* mask = (unsigned short*)(ws + 57454592);          // 18,939,904
  unsigned short* aob  = xbf;  // attention output bf16 [8200][768]

  conv_kernel<<<2048, 256, 0, stream>>>(x, xbf, (MROWS * Dd) / 4);
  conv_kernel<<<1728, 256, 0, stream>>>(Wqkv, wqb, (3 * Dd * Dd) / 4);
  conv_kernel<<<576, 256, 0, stream>>>(Wproj, wpb, (Dd * Dd) / 4);
  pw_kernel<<<Bq, 256, 0, stream>>>(transf, pw);
  mask_kernel<<<dim3(NP, Bq), 256, 0, stream>>>(graph, pw, mask);
  padzero_kernel<<<96, 256, 0, stream>>>(Qb, Kb, Vb);
  qkv_gemm_kernel<<<dim3(65, 18), 256, 0, stream>>>(xbf, wqb, bqkv, Qb, Kb, Vb);
  attn_kernel<<<1632, 256, 0, stream>>>(Qb, Kb, Vb, mask, aob);
  proj_gemm_kernel<<<dim3(65, 6), 256, 0, stream>>>(aob, wpb, bproj, out);
}

// Round 4
// 206.070 us; speedup vs baseline: 1.9485x; 1.1041x over previous
//
#include <hip/hip_runtime.h>
#include <stdint.h>

// ---------------- constants ----------------
constexpr int Bq = 8, Nn = 1025, Dd = 768, Hh = 12, HDd = 64, Pp = 1024;
constexpr int NP = 1088;              // padded N = 17*64
constexpr int MROWS = Bq * Nn;        // 8200
constexpr float EPSI = 1e-6f;

typedef __attribute__((ext_vector_type(8))) short bfrag;   // 8 bf16 = 4 VGPR
typedef __attribute__((ext_vector_type(4))) float ffrag;   // 4 f32
typedef __attribute__((ext_vector_type(4))) float f4;
typedef __attribute__((ext_vector_type(4))) unsigned short us4;

#define MFMA16(a, b, c) __builtin_amdgcn_mfma_f32_16x16x32_bf16((a), (b), (c), 0, 0, 0)

#if __has_builtin(__builtin_amdgcn_exp2f)
#define EXP2(x) __builtin_amdgcn_exp2f(x)
#else
#define EXP2(x) exp2f(x)
#endif

__device__ __forceinline__ unsigned short f2bf(float f) {
  union { float f; uint32_t u; } v{f};
  uint32_t u = v.u;
  return (unsigned short)((u + 0x7fffu + ((u >> 16) & 1u)) >> 16);  // RNE
}
__device__ __forceinline__ float bf2f(unsigned short s) {
  union { uint32_t u; float f; } v; v.u = ((uint32_t)s) << 16; return v.f;
}
// pack 2 f32 -> 2 bf16 in one u32 (lo = a, hi = b), RNE
__device__ __forceinline__ uint32_t pkbf(float a, float b) {
  uint32_t r;
  asm("v_cvt_pk_bf16_f32 %0, %1, %2" : "=v"(r) : "v"(a), "v"(b));
  return r;
}

// async global -> LDS, 16B per lane. LDS dest must be wave-uniform base + lane*16.
__device__ __forceinline__ void gload16(const void* g, void* l) {
  __builtin_amdgcn_global_load_lds((const __attribute__((address_space(1))) unsigned int*)g,
                                   (__attribute__((address_space(3))) unsigned int*)l, 16, 0, 0);
}

// ---------------- fp32 -> bf16 conversion ----------------
__global__ __launch_bounds__(256) void conv_kernel(const float* __restrict__ src,
                                                   unsigned short* __restrict__ dst, int n4) {
  int idx = blockIdx.x * blockDim.x + threadIdx.x;
  int stride = gridDim.x * blockDim.x;
  for (int i = idx; i < n4; i += stride) {
    f4 v = ((const f4*)src)[i];
    us4 o; o[0] = f2bf(v[0]); o[1] = f2bf(v[1]); o[2] = f2bf(v[2]); o[3] = f2bf(v[3]);
    ((us4*)dst)[i] = o;
  }
}

// ---------------- pw = t / (sum(t)+eps) ----------------
__global__ __launch_bounds__(256) void pw_kernel(const float* __restrict__ tr, float* __restrict__ pw) {
  int b = blockIdx.x;
  __shared__ float red[256];
  float s = 0.f;
  for (int j = threadIdx.x; j < Pp; j += 256) s += tr[b * Pp + j];
  red[threadIdx.x] = s; __syncthreads();
  for (int o = 128; o > 0; o >>= 1) { if (threadIdx.x < o) red[threadIdx.x] += red[threadIdx.x + o]; __syncthreads(); }
  float inv = 1.f / (red[0] + EPSI);
  for (int j = threadIdx.x; j < Pp; j += 256) pw[b * Pp + j] = tr[b * Pp + j] * inv;
}

// ---------------- mask bf16 [B][NP][NP], zero padded ----------------
__global__ __launch_bounds__(256) void mask_kernel(const float* __restrict__ graph,
                                                   const float* __restrict__ pw,
                                                   unsigned short* __restrict__ mask) {
  int i = blockIdx.x, b = blockIdx.y;
  unsigned short* mrow = mask + ((size_t)b * NP + i) * NP;
  if (i >= Nn) { for (int j = threadIdx.x; j < NP; j += 256) mrow[j] = 0; return; }
  if (i == 0) {
    for (int j = threadIdx.x; j < NP; j += 256) {
      float v = (j == 0) ? 1.f : (j <= Pp ? pw[b * Pp + j - 1] : 0.f);
      mrow[j] = f2bf(v);
    }
  } else {
    const float* grow = graph + ((size_t)b * Pp + (i - 1)) * Pp;
    for (int j = threadIdx.x; j < NP; j += 256) {
      float v = (j == 0) ? pw[b * Pp + i - 1] : (j <= Pp ? grow[j - 1] : 0.f);
      mrow[j] = f2bf(v);
    }
  }
}

// ---------------- zero pad rows of Q/K and pad cols of VT ----------------
__global__ __launch_bounds__(256) void padzero_kernel(unsigned short* __restrict__ Qo,
                                                      unsigned short* __restrict__ Ko,
                                                      unsigned short* __restrict__ Vo) {
  int bh = blockIdx.x;  // 0..95
  unsigned short* qp = Qo + ((size_t)bh * NP + Nn) * 64;
  unsigned short* kp = Ko + ((size_t)bh * NP + Nn) * 64;
  for (int idx = threadIdx.x; idx < (NP - Nn) * 64; idx += 256) { qp[idx] = 0; kp[idx] = 0; }
  unsigned short* vp = Vo + (size_t)bh * 64 * NP;
  for (int idx = threadIdx.x; idx < 64 * (NP - Nn); idx += 256) {
    int d = idx / (NP - Nn), j = Nn + (idx - d * (NP - Nn));
    vp[(size_t)d * NP + j] = 0;
  }
}

// ---------------- GEMM core: 128x128 tile, BK=64, K=768, bf16 MFMA ----------------
// 2-phase double-buffered pipeline (T3-min): stage tile t+1 into alternate LDS buffer
// via global_load_lds BEFORE computing tile t; one vmcnt(0) + raw s_barrier per K-step.
// LDS: per buffer, A tile [128 rows][8 chunk-slots] uint4 + B same at +1024.
// Slot p of row r holds global chunk p^(r&7) (pre-swizzled GLOBAL address, linear LDS dest).
__device__ __forceinline__ void gemm_main(const unsigned short* __restrict__ A, int rowA0, int rowAmax,
                                          const unsigned short* __restrict__ Bw, int rowB0,
                                          uint4* lds, ffrag acc[4][4], int tid) {
  const int l = tid & 63, lm = l & 15, lg = l >> 4, w = tid >> 6, wr = w >> 1, wc = w & 1;
  const unsigned short* aS[4]; const unsigned short* bS[4];
#pragma unroll
  for (int q = 0; q < 4; q++) {
    int c = tid + 256 * q, r = c >> 3, p = c & 7, g = p ^ (r & 7);
    int ra = rowA0 + r; if (ra > rowAmax) ra = rowAmax;
    aS[q] = A + (size_t)ra * 768 + 8 * g;
    bS[q] = Bw + (size_t)(rowB0 + r) * 768 + 8 * g;
  }
  uint4* buf0 = lds;
  uint4* buf1 = lds + 2048;
  // prologue: stage tile 0 into buf0
#pragma unroll
  for (int q = 0; q < 4; q++) {
    gload16(aS[q], buf0 + tid + 256 * q);
    gload16(bS[q], buf0 + 1024 + tid + 256 * q);
    aS[q] += 64; bS[q] += 64;
  }
  asm volatile("s_waitcnt vmcnt(0)" ::: "memory");
  __builtin_amdgcn_sched_barrier(0);
  __builtin_amdgcn_s_barrier();
#pragma unroll 1
  for (int kt = 0; kt < 12; kt++) {
    uint4* cur = (kt & 1) ? buf1 : buf0;
    uint4* nxt = (kt & 1) ? buf0 : buf1;
    if (kt < 11) {
#pragma unroll
      for (int q = 0; q < 4; q++) {
        gload16(aS[q], nxt + tid + 256 * q);
        gload16(bS[q], nxt + 1024 + tid + 256 * q);
        aS[q] += 64; bS[q] += 64;
      }
    }
    const bfrag* LA = (const bfrag*)cur;
    const bfrag* LB = (const bfrag*)(cur + 1024);
    bfrag af[4][2], bf_[4][2];
#pragma unroll
    for (int am = 0; am < 4; am++) {
      int row = wr * 64 + am * 16 + lm;
      af[am][0] = LA[row * 8 + ((0 + lg) ^ (row & 7))];
      af[am][1] = LA[row * 8 + ((4 + lg) ^ (row & 7))];
    }
#pragma unroll
    for (int an = 0; an < 4; an++) {
      int row = wc * 64 + an * 16 + lm;
      bf_[an][0] = LB[row * 8 + ((0 + lg) ^ (row & 7))];
      bf_[an][1] = LB[row * 8 + ((4 + lg) ^ (row & 7))];
    }
#pragma unroll
    for (int am = 0; am < 4; am++)
#pragma unroll
      for (int an = 0; an < 4; an++) {
        acc[am][an] = MFMA16(af[am][0], bf_[an][0], acc[am][an]);
        acc[am][an] = MFMA16(af[am][1], bf_[an][1], acc[am][an]);
      }
    // all ds_read results consumed by MFMAs above (lgkm implicitly drained);
    // wait next tile's loads landed, then one barrier per K-step.
    asm volatile("s_waitcnt vmcnt(0)" ::: "memory");
    __builtin_amdgcn_sched_barrier(0);
    __builtin_amdgcn_s_barrier();
  }
}

// bijective XCD-chunked mapping (m204): orig -> wg such that each XCD gets a
// contiguous chunk of the y-fastest tile ordering (A-panel chunk stays L2-resident).
__device__ __forceinline__ int xcd_chunk_map(int orig, int nwg) {
  int qq = nwg >> 3, rr = nwg & 7;
  int xcd = orig & 7, idx = orig >> 3;
  int base = (xcd < rr) ? xcd * (qq + 1) : rr * (qq + 1) + (xcd - rr) * qq;
  return base + idx;
}

// ---------------- kernel 1: QKV GEMM + scatter epilogue ----------------
__global__ __launch_bounds__(256) void qkv_gemm_kernel(const unsigned short* __restrict__ X,
                                                       const unsigned short* __restrict__ W,
                                                       const float* __restrict__ bias,
                                                       unsigned short* __restrict__ Qo,
                                                       unsigned short* __restrict__ Ko,
                                                       unsigned short* __restrict__ Vo) {
  __shared__ uint4 lds[4096];
  int tid = threadIdx.x;
  int wg = xcd_chunk_map(blockIdx.x, 65 * 18);
  int xt = wg / 18, yt = wg - 18 * xt;   // y-fastest: XCD chunk = ~8 x-tiles x all 18 y
  ffrag zero4 = {0.f, 0.f, 0.f, 0.f};
  ffrag acc[4][4];
#pragma unroll
  for (int i = 0; i < 4; i++)
#pragma unroll
    for (int j = 0; j < 4; j++) acc[i][j] = zero4;
  gemm_main(X, xt * 128, MROWS - 1, W, yt * 128, lds, acc, tid);
  const int l = tid & 63, lm = l & 15, lg = l >> 4, w = tid >> 6, wr = w >> 1, wc = w & 1;
#pragma unroll
  for (int an = 0; an < 4; an++) {
    int gc = yt * 128 + wc * 64 + an * 16 + lm;
    int which = gc / 768, rr = gc - which * 768, h = rr >> 6, hd = rr & 63;
    float bv = bias[gc];
#pragma unroll
    for (int am = 0; am < 4; am++) {
      int grb = xt * 128 + wr * 64 + am * 16 + 4 * lg;
#pragma unroll
      for (int r = 0; r < 4; r++) {
        int gr = grb + r;
        if (gr >= MROWS) continue;
        int b = gr / Nn, i = gr - b * Nn;
        size_t bh = (size_t)(b * Hh + h);
        float v = acc[am][an][r] + bv;
        // Q prescale folds softmax scale AND log2(e) for exp2-domain softmax:
        // 0.125 * 1.44269504 = 0.18033688
        if (which == 0)      Qo[(bh * NP + i) * 64 + hd] = f2bf(v * 0.18033688f);
        else if (which == 1) Ko[(bh * NP + i) * 64 + hd] = f2bf(v);
        else                 Vo[(bh * 64 + hd) * NP + i] = f2bf(v);           // V transposed
      }
    }
  }
}

// ---------------- kernel 3: proj GEMM + bias -> fp32 out ----------------
__global__ __launch_bounds__(256) void proj_gemm_kernel(const unsigned short* __restrict__ A,
                                                        const unsigned short* __restrict__ W,
                                                        const float* __restrict__ bias,
                                                        float* __restrict__ out) {
  __shared__ uint4 lds[4096];
  int tid = threadIdx.x;
  int wg = xcd_chunk_map(blockIdx.x, 65 * 6);
  int xt = wg / 6, yt = wg - 6 * xt;
  ffrag zero4 = {0.f, 0.f, 0.f, 0.f};
  ffrag acc[4][4];
#pragma unroll
  for (int i = 0; i < 4; i++)
#pragma unroll
    for (int j = 0; j < 4; j++) acc[i][j] = zero4;
  gemm_main(A, xt * 128, MROWS - 1, W, yt * 128, lds, acc, tid);
  const int l = tid & 63, lm = l & 15, lg = l >> 4, w = tid >> 6, wr = w >> 1, wc = w & 1;
#pragma unroll
  for (int an = 0; an < 4; an++) {
    int gc = yt * 128 + wc * 64 + an * 16 + lm;
    float bv = bias[gc];
#pragma unroll
    for (int am = 0; am < 4; am++) {
      int grb = xt * 128 + wr * 64 + am * 16 + 4 * lg;
#pragma unroll
      for (int r = 0; r < 4; r++) {
        int gr = grb + r;
        if (gr >= MROWS) continue;
        out[(size_t)gr * 768 + gc] = acc[am][an][r] + bv;
      }
    }
  }
}

// ---------------- kernel 2: fused masked attention, swapped-QK^T, no-max softmax ----------------
// Lane owns q-row i = i0 + lm; j-coverage per lane: {16*jm + 4*lg + r}.
// s in exp2 domain (Q pre-scaled by 0.125*log2e). No online max (|s| ~ 0.3 << fp32 range).
// out = (sum e2^s * m * v) / (sum e2^s * m + eps * sum e2^s)  == reference exactly.
__global__ __launch_bounds__(256) void attn_kernel(const unsigned short* __restrict__ Qg,
                                                   const unsigned short* __restrict__ Kg,
                                                   const unsigned short* __restrict__ Vg,
                                                   const unsigned short* __restrict__ Mg,
                                                   unsigned short* __restrict__ Og) {
  __shared__ uint4 smem[1536];  // K 8KB | V 8KB | P 4x2KB
  int tid = threadIdx.x, w = tid >> 6, l = tid & 63, lm = l & 15, lg = l >> 4;
  // XCD swizzle: b = bx & 7 pins batch->XCD (round-robin dispatch); within XCD h varies fastest
  // so the 12 heads sharing a mask row-tile are consecutive on the same L2.
  int bx = blockIdx.x;
  int b = bx & 7, t5 = bx >> 3;
  int h = t5 % 12, ib = t5 / 12;
  size_t bh = (size_t)(b * Hh + h);
  const unsigned short* Qb = Qg + bh * NP * 64;
  const unsigned short* Kb = Kg + bh * NP * 64;
  const unsigned short* Vb = Vg + bh * 64 * NP;
  int i0 = ib * 64 + w * 16;
  int irow = i0 + lm;
  const unsigned short* Mrow = Mg + (size_t)b * NP * NP + (size_t)irow * NP;

  bfrag qf0 = *(const bfrag*)(Qb + (size_t)irow * 64 + 8 * lg);
  bfrag qf1 = *(const bfrag*)(Qb + (size_t)irow * 64 + 32 + 8 * lg);

  ffrag zero4 = {0.f, 0.f, 0.f, 0.f};
  ffrag oacc[4] = {zero4, zero4, zero4, zero4};
  float Zp = 0.f, Tp = 0.f;

  int rS = tid >> 3, pS = tid & 7, gS = pS ^ (rS & 7);
  const unsigned short* kS = Kb + rS * 64 + 8 * gS;
  const unsigned short* vS = Vb + (size_t)rS * NP + 8 * gS;
  uint4* ldsK4 = smem; uint4* ldsV4 = smem + 512;
  char* Pbase = (char*)(smem + 1024) + w * 2048;   // per-wave P tile [16 i][64 j] bf16, chunk-XOR
  const bfrag* LK = (const bfrag*)ldsK4;
  const bfrag* LV = (const bfrag*)ldsV4;

#pragma unroll 1
  for (int t = 0; t < 17; t++) {
    // K/V reg-staged prefetch (issued before barrier -> overlaps prev tile compute)
    uint4 k0 = *(const uint4*)kS, k1 = *(const uint4*)(kS + 2048);
    uint4 v0 = *(const uint4*)vS, v1 = *(const uint4*)(vS + 32 * NP);
    // mask for this tile: 4x 8B vector loads (j = 16*jm + 4*lg + 0..3), issued early
    int j0 = t * 64;
    us4 mv[4];
#pragma unroll
    for (int jm = 0; jm < 4; jm++) mv[jm] = *(const us4*)(Mrow + j0 + 16 * jm + 4 * lg);
    __syncthreads();
    ldsK4[tid] = k0; ldsK4[tid + 256] = k1; ldsV4[tid] = v0; ldsV4[tid + 256] = v1;
    __syncthreads();
    kS += 64 * 64; vS += 64;

    // --- QK^T (swapped): s[jm][r] = S[j0+16jm+4lg+r][i0+lm] ---
    ffrag s[4];
#pragma unroll
    for (int jm = 0; jm < 4; jm++) {
      int row = jm * 16 + lm;
      bfrag a0 = LK[row * 8 + ((0 + lg) ^ (row & 7))];
      bfrag a1 = LK[row * 8 + ((4 + lg) ^ (row & 7))];
      ffrag a = zero4;
      a = MFMA16(a0, qf0, a);
      a = MFMA16(a1, qf1, a);
      s[jm] = a;
    }
    // --- p = exp2(s); pm = p*mask; accumulate Z,T; pack + write P ---
#pragma unroll
    for (int jm = 0; jm < 4; jm++) {
      float p0 = EXP2(s[jm][0]), p1 = EXP2(s[jm][1]), p2 = EXP2(s[jm][2]), p3 = EXP2(s[jm][3]);
      Zp += (p0 + p1) + (p2 + p3);
      float q0 = p0 * bf2f(mv[jm][0]), q1 = p1 * bf2f(mv[jm][1]);
      float q2 = p2 * bf2f(mv[jm][2]), q3 = p3 * bf2f(mv[jm][3]);
      Tp += (q0 + q1) + (q2 + q3);
      uint2 pk; pk.x = pkbf(q0, q1); pk.y = pkbf(q2, q3);
      int cpos = (((jm << 1) | (lg >> 1)) ^ (lm & 7));
      *(uint2*)(Pbase + lm * 128 + cpos * 16 + 8 * (lg & 1)) = pk;
    }
    // --- PV: A = P[16i][64j] (chunk-XOR read), B = V^T rows from LDS ---
#pragma unroll
    for (int ks = 0; ks < 2; ks++) {
      bfrag pa = *(const bfrag*)(Pbase + lm * 128 + ((((ks << 2) | lg)) ^ (lm & 7)) * 16);
#pragma unroll
      for (int dm = 0; dm < 4; dm++) {
        int vrow = dm * 16 + lm;
        bfrag vb = LV[vrow * 8 + ((ks * 4 + lg) ^ (vrow & 7))];
        oacc[dm] = MFMA16(pa, vb, oacc[dm]);
      }
    }
  }
  // --- finalize: reduce Z,T across lg lanes; broadcast per-row denominators ---
  Zp += __shfl_xor(Zp, 16); Zp += __shfl_xor(Zp, 32);
  Tp += __shfl_xor(Tp, 16); Tp += __shfl_xor(Tp, 32);
  float dn_row = 1.f / (Tp + EPSI * Zp);   // valid at every lane for row i0 + lm
  float dn[4];
#pragma unroll
  for (int r = 0; r < 4; r++) dn[r] = __shfl(dn_row, 4 * lg + r);  // row of oacc reg r
#pragma unroll
  for (int dm = 0; dm < 4; dm++)
#pragma unroll
    for (int r = 0; r < 4; r++) {
      int i = i0 + 4 * lg + r;
      if (i < Nn) Og[((size_t)(b * Nn + i)) * Dd + h * 64 + dm * 16 + lm] = f2bf(oacc[dm][r] * dn[r]);
    }
}

// ---------------- launch ----------------
extern "C" void kernel_launch(void* const* d_in, const int* in_sizes, int n_in,
                              void* d_out, int out_size, void* d_ws, size_t ws_size,
                              hipStream_t stream) {
  const float* x      = (const float*)d_in[0];
  const float* graph  = (const float*)d_in[1];
  const float* transf = (const float*)d_in[2];
  const float* Wqkv   = (const float*)d_in[3];
  const float* bqkv   = (const float*)d_in[4];
  const float* Wproj  = (const float*)d_in[5];
  const float* bproj  = (const float*)d_in[6];
  float* out = (float*)d_out;
  char* ws = (char*)d_ws;

  // ws layout (bytes); total ~76.4 MB. attn_out aliases x_bf16 (disjoint lifetimes).
  unsigned short* xbf  = (unsigned short*)(ws + 0);                 // 12,595,200 (also attn_out)
  unsigned short* wqb  = (unsigned short*)(ws + 12595200);          //  3,538,944
  unsigned short* wpb  = (unsigned short*)(ws + 16134144);          //  1,179,648
  unsigned short* Qb   = (unsigned short*)(ws + 17313792);          // 13,369,344
  unsigned short* Kb   = (unsigned short*)(ws + 30683136);          // 13,369,344
  unsigned short* Vb   = (unsigned short*)(ws + 44052480);          // 13,369,344
  float*          pw   = (float*)(ws + 57421824);                   //     32,768
  unsigned short* mask = (unsigned short*)(ws + 57454592);          // 18,939,904
  unsigned short* aob  = xbf;  // attention output bf16 [8200][768]

  conv_kernel<<<2048, 256, 0, stream>>>(x, xbf, (MROWS * Dd) / 4);
  conv_kernel<<<1728, 256, 0, stream>>>(Wqkv, wqb, (3 * Dd * Dd) / 4);
  conv_kernel<<<576, 256, 0, stream>>>(Wproj, wpb, (Dd * Dd) / 4);
  pw_kernel<<<Bq, 256, 0, stream>>>(transf, pw);
  mask_kernel<<<dim3(NP, Bq), 256, 0, stream>>>(graph, pw, mask);
  padzero_kernel<<<96, 256, 0, stream>>>(Qb, Kb, Vb);
  qkv_gemm_kernel<<<65 * 18, 256, 0, stream>>>(xbf, wqb, bqkv, Qb, Kb, Vb);
  attn_kernel<<<1632, 256, 0, stream>>>(Qb, Kb, Vb, mask, aob);
  proj_gemm_kernel<<<65 * 6, 256, 0, stream>>>(aob, wpb, bproj, out);
}

// Round 5
// 205.349 us; speedup vs baseline: 1.9553x; 1.0035x over previous
//
#include <hip/hip_runtime.h>
#include <stdint.h>

// ---------------- constants ----------------
constexpr int Bq = 8, Nn = 1025, Dd = 768, Hh = 12, HDd = 64, Pp = 1024;
constexpr int NP = 1088;              // padded N = 17*64
constexpr int MROWS = Bq * Nn;        // 8200
constexpr float EPSI = 1e-6f;

typedef __attribute__((ext_vector_type(8))) short bfrag;   // 8 bf16 = 4 VGPR
typedef __attribute__((ext_vector_type(4))) float ffrag;   // 4 f32
typedef __attribute__((ext_vector_type(4))) float f4;
typedef __attribute__((ext_vector_type(4))) unsigned short us4;

#define MFMA16(a, b, c) __builtin_amdgcn_mfma_f32_16x16x32_bf16((a), (b), (c), 0, 0, 0)

#if __has_builtin(__builtin_amdgcn_exp2f)
#define EXP2(x) __builtin_amdgcn_exp2f(x)
#else
#define EXP2(x) exp2f(x)
#endif

__device__ __forceinline__ unsigned short f2bf(float f) {
  union { float f; uint32_t u; } v{f};
  uint32_t u = v.u;
  return (unsigned short)((u + 0x7fffu + ((u >> 16) & 1u)) >> 16);  // RNE
}
__device__ __forceinline__ float bf2f(unsigned short s) {
  union { uint32_t u; float f; } v; v.u = ((uint32_t)s) << 16; return v.f;
}
// pack 2 f32 -> 2 bf16 in one u32 (lo = a, hi = b), RNE
__device__ __forceinline__ uint32_t pkbf(float a, float b) {
  uint32_t r;
  asm("v_cvt_pk_bf16_f32 %0, %1, %2" : "=v"(r) : "v"(a), "v"(b));
  return r;
}

// async global -> LDS, 16B per lane. LDS dest must be wave-uniform base + lane*16.
__device__ __forceinline__ void gload16(const void* g, void* l) {
  __builtin_amdgcn_global_load_lds((const __attribute__((address_space(1))) unsigned int*)g,
                                   (__attribute__((address_space(3))) unsigned int*)l, 16, 0, 0);
}

// ---------------- fp32 -> bf16 conversion ----------------
__global__ __launch_bounds__(256) void conv_kernel(const float* __restrict__ src,
                                                   unsigned short* __restrict__ dst, int n4) {
  int idx = blockIdx.x * blockDim.x + threadIdx.x;
  int stride = gridDim.x * blockDim.x;
  for (int i = idx; i < n4; i += stride) {
    f4 v = ((const f4*)src)[i];
    us4 o; o[0] = f2bf(v[0]); o[1] = f2bf(v[1]); o[2] = f2bf(v[2]); o[3] = f2bf(v[3]);
    ((us4*)dst)[i] = o;
  }
}

// ---------------- pw = t / (sum(t)+eps) ----------------
__global__ __launch_bounds__(256) void pw_kernel(const float* __restrict__ tr, float* __restrict__ pw) {
  int b = blockIdx.x;
  __shared__ float red[256];
  float s = 0.f;
  for (int j = threadIdx.x; j < Pp; j += 256) s += tr[b * Pp + j];
  red[threadIdx.x] = s; __syncthreads();
  for (int o = 128; o > 0; o >>= 1) { if (threadIdx.x < o) red[threadIdx.x] += red[threadIdx.x + o]; __syncthreads(); }
  float inv = 1.f / (red[0] + EPSI);
  for (int j = threadIdx.x; j < Pp; j += 256) pw[b * Pp + j] = tr[b * Pp + j] * inv;
}

// ---------------- mask bf16 [B][NP][NP], zero padded ----------------
__global__ __launch_bounds__(256) void mask_kernel(const float* __restrict__ graph,
                                                   const float* __restrict__ pw,
                                                   unsigned short* __restrict__ mask) {
  int i = blockIdx.x, b = blockIdx.y;
  unsigned short* mrow = mask + ((size_t)b * NP + i) * NP;
  if (i >= Nn) { for (int j = threadIdx.x; j < NP; j += 256) mrow[j] = 0; return; }
  if (i == 0) {
    for (int j = threadIdx.x; j < NP; j += 256) {
      float v = (j == 0) ? 1.f : (j <= Pp ? pw[b * Pp + j - 1] : 0.f);
      mrow[j] = f2bf(v);
    }
  } else {
    const float* grow = graph + ((size_t)b * Pp + (i - 1)) * Pp;
    for (int j = threadIdx.x; j < NP; j += 256) {
      float v = (j == 0) ? pw[b * Pp + i - 1] : (j <= Pp ? grow[j - 1] : 0.f);
      mrow[j] = f2bf(v);
    }
  }
}

// ---------------- zero pad rows of Q/K and pad cols of VT ----------------
__global__ __launch_bounds__(256) void padzero_kernel(unsigned short* __restrict__ Qo,
                                                      unsigned short* __restrict__ Ko,
                                                      unsigned short* __restrict__ Vo) {
  int bh = blockIdx.x;  // 0..95
  unsigned short* qp = Qo + ((size_t)bh * NP + Nn) * 64;
  unsigned short* kp = Ko + ((size_t)bh * NP + Nn) * 64;
  for (int idx = threadIdx.x; idx < (NP - Nn) * 64; idx += 256) { qp[idx] = 0; kp[idx] = 0; }
  unsigned short* vp = Vo + (size_t)bh * 64 * NP;
  for (int idx = threadIdx.x; idx < 64 * (NP - Nn); idx += 256) {
    int d = idx / (NP - Nn), j = Nn + (idx - d * (NP - Nn));
    vp[(size_t)d * NP + j] = 0;
  }
}

// ---------------- GEMM core: 128x128 tile, BK=64, K=768, bf16 MFMA ----------------
// 2-phase double-buffered pipeline (T3-min): stage tile t+1 into alternate LDS buffer
// via global_load_lds BEFORE computing tile t; one vmcnt(0) + raw s_barrier per K-step.
// LDS: per buffer, A tile [128 rows][8 chunk-slots] uint4 + B same at +1024.
// Slot p of row r holds global chunk p^(r&7) (pre-swizzled GLOBAL address, linear LDS dest).
__device__ __forceinline__ void gemm_main(const unsigned short* __restrict__ A, int rowA0, int rowAmax,
                                          const unsigned short* __restrict__ Bw, int rowB0,
                                          uint4* lds, ffrag acc[4][4], int tid) {
  const int l = tid & 63, lm = l & 15, lg = l >> 4, w = tid >> 6, wr = w >> 1, wc = w & 1;
  const unsigned short* aS[4]; const unsigned short* bS[4];
#pragma unroll
  for (int q = 0; q < 4; q++) {
    int c = tid + 256 * q, r = c >> 3, p = c & 7, g = p ^ (r & 7);
    int ra = rowA0 + r; if (ra > rowAmax) ra = rowAmax;
    aS[q] = A + (size_t)ra * 768 + 8 * g;
    bS[q] = Bw + (size_t)(rowB0 + r) * 768 + 8 * g;
  }
  uint4* buf0 = lds;
  uint4* buf1 = lds + 2048;
  // prologue: stage tile 0 into buf0
#pragma unroll
  for (int q = 0; q < 4; q++) {
    gload16(aS[q], buf0 + tid + 256 * q);
    gload16(bS[q], buf0 + 1024 + tid + 256 * q);
    aS[q] += 64; bS[q] += 64;
  }
  asm volatile("s_waitcnt vmcnt(0)" ::: "memory");
  __builtin_amdgcn_sched_barrier(0);
  __builtin_amdgcn_s_barrier();
#pragma unroll 1
  for (int kt = 0; kt < 12; kt++) {
    uint4* cur = (kt & 1) ? buf1 : buf0;
    uint4* nxt = (kt & 1) ? buf0 : buf1;
    if (kt < 11) {
#pragma unroll
      for (int q = 0; q < 4; q++) {
        gload16(aS[q], nxt + tid + 256 * q);
        gload16(bS[q], nxt + 1024 + tid + 256 * q);
        aS[q] += 64; bS[q] += 64;
      }
    }
    const bfrag* LA = (const bfrag*)cur;
    const bfrag* LB = (const bfrag*)(cur + 1024);
    bfrag af[4][2], bf_[4][2];
#pragma unroll
    for (int am = 0; am < 4; am++) {
      int row = wr * 64 + am * 16 + lm;
      af[am][0] = LA[row * 8 + ((0 + lg) ^ (row & 7))];
      af[am][1] = LA[row * 8 + ((4 + lg) ^ (row & 7))];
    }
#pragma unroll
    for (int an = 0; an < 4; an++) {
      int row = wc * 64 + an * 16 + lm;
      bf_[an][0] = LB[row * 8 + ((0 + lg) ^ (row & 7))];
      bf_[an][1] = LB[row * 8 + ((4 + lg) ^ (row & 7))];
    }
#pragma unroll
    for (int am = 0; am < 4; am++)
#pragma unroll
      for (int an = 0; an < 4; an++) {
        acc[am][an] = MFMA16(af[am][0], bf_[an][0], acc[am][an]);
        acc[am][an] = MFMA16(af[am][1], bf_[an][1], acc[am][an]);
      }
    // all ds_read results consumed by MFMAs above (lgkm implicitly drained);
    // wait next tile's loads landed, then one barrier per K-step.
    asm volatile("s_waitcnt vmcnt(0)" ::: "memory");
    __builtin_amdgcn_sched_barrier(0);
    __builtin_amdgcn_s_barrier();
  }
}

// bijective XCD-chunked mapping (m204): orig -> wg such that each XCD gets a
// contiguous chunk of the y-fastest tile ordering (A-panel chunk stays L2-resident).
__device__ __forceinline__ int xcd_chunk_map(int orig, int nwg) {
  int qq = nwg >> 3, rr = nwg & 7;
  int xcd = orig & 7, idx = orig >> 3;
  int base = (xcd < rr) ? xcd * (qq + 1) : rr * (qq + 1) + (xcd - rr) * qq;
  return base + idx;
}

// ---------------- kernel 1: QKV GEMM + scatter epilogue ----------------
__global__ __launch_bounds__(256) void qkv_gemm_kernel(const unsigned short* __restrict__ X,
                                                       const unsigned short* __restrict__ W,
                                                       const float* __restrict__ bias,
                                                       unsigned short* __restrict__ Qo,
                                                       unsigned short* __restrict__ Ko,
                                                       unsigned short* __restrict__ Vo) {
  __shared__ uint4 lds[4096];
  int tid = threadIdx.x;
  int wg = xcd_chunk_map(blockIdx.x, 65 * 18);
  int xt = wg / 18, yt = wg - 18 * xt;   // y-fastest: XCD chunk = ~8 x-tiles x all 18 y
  ffrag zero4 = {0.f, 0.f, 0.f, 0.f};
  ffrag acc[4][4];
#pragma unroll
  for (int i = 0; i < 4; i++)
#pragma unroll
    for (int j = 0; j < 4; j++) acc[i][j] = zero4;
  gemm_main(X, xt * 128, MROWS - 1, W, yt * 128, lds, acc, tid);
  const int l = tid & 63, lm = l & 15, lg = l >> 4, w = tid >> 6, wr = w >> 1, wc = w & 1;
#pragma unroll
  for (int an = 0; an < 4; an++) {
    int gc = yt * 128 + wc * 64 + an * 16 + lm;
    int which = gc / 768, rr = gc - which * 768, h = rr >> 6, hd = rr & 63;
    float bv = bias[gc];
#pragma unroll
    for (int am = 0; am < 4; am++) {
      int grb = xt * 128 + wr * 64 + am * 16 + 4 * lg;
#pragma unroll
      for (int r = 0; r < 4; r++) {
        int gr = grb + r;
        if (gr >= MROWS) continue;
        int b = gr / Nn, i = gr - b * Nn;
        size_t bh = (size_t)(b * Hh + h);
        float v = acc[am][an][r] + bv;
        // Q prescale folds softmax scale AND log2(e) for exp2-domain softmax:
        // 0.125 * 1.44269504 = 0.18033688
        if (which == 0)      Qo[(bh * NP + i) * 64 + hd] = f2bf(v * 0.18033688f);
        else if (which == 1) Ko[(bh * NP + i) * 64 + hd] = f2bf(v);
        else                 Vo[(bh * 64 + hd) * NP + i] = f2bf(v);           // V transposed
      }
    }
  }
}

// ---------------- kernel 3: proj GEMM + bias -> fp32 out ----------------
__global__ __launch_bounds__(256) void proj_gemm_kernel(const unsigned short* __restrict__ A,
                                                        const unsigned short* __restrict__ W,
                                                        const float* __restrict__ bias,
                                                        float* __restrict__ out) {
  __shared__ uint4 lds[4096];
  int tid = threadIdx.x;
  int wg = xcd_chunk_map(blockIdx.x, 65 * 6);
  int xt = wg / 6, yt = wg - 6 * xt;
  ffrag zero4 = {0.f, 0.f, 0.f, 0.f};
  ffrag acc[4][4];
#pragma unroll
  for (int i = 0; i < 4; i++)
#pragma unroll
    for (int j = 0; j < 4; j++) acc[i][j] = zero4;
  gemm_main(A, xt * 128, MROWS - 1, W, yt * 128, lds, acc, tid);
  const int l = tid & 63, lm = l & 15, lg = l >> 4, w = tid >> 6, wr = w >> 1, wc = w & 1;
#pragma unroll
  for (int an = 0; an < 4; an++) {
    int gc = yt * 128 + wc * 64 + an * 16 + lm;
    float bv = bias[gc];
#pragma unroll
    for (int am = 0; am < 4; am++) {
      int grb = xt * 128 + wr * 64 + am * 16 + 4 * lg;
#pragma unroll
      for (int r = 0; r < 4; r++) {
        int gr = grb + r;
        if (gr >= MROWS) continue;
        out[(size_t)gr * 768 + gc] = acc[am][an][r] + bv;
      }
    }
  }
}

// ---------------- kernel 2: fused masked attention, swapped-QK^T, pipelined ----------------
// Lane owns q-row i = i0 + lm; j-coverage per lane: {16*jm + 4*lg + r}.
// s in exp2 domain (Q pre-scaled by 0.125*log2e). No online max (|s| small).
// Denominator: T = sum e2^s*m; eps*Z term dropped (rel err ~2e-6 << tolerance).
// Pipeline: double-buffered K/V via global_load_lds; stage t+1 before computing t;
// one vmcnt(0)+s_barrier per tile. Mask prefetched one tile ahead into regs.
__global__ __launch_bounds__(256) void attn_kernel(const unsigned short* __restrict__ Qg,
                                                   const unsigned short* __restrict__ Kg,
                                                   const unsigned short* __restrict__ Vg,
                                                   const unsigned short* __restrict__ Mg,
                                                   unsigned short* __restrict__ Og) {
  __shared__ uint4 smem[2560];  // K dbuf 2x8KB | V dbuf 2x8KB | P 4x2KB  = 40KB
  int tid = threadIdx.x, w = tid >> 6, l = tid & 63, lm = l & 15, lg = l >> 4;
  // XCD swizzle: b = bx & 7 pins batch->XCD (round-robin dispatch); within XCD h varies fastest.
  int bx = blockIdx.x;
  int b = bx & 7, t5 = bx >> 3;
  int h = t5 % 12, ib = t5 / 12;
  size_t bh = (size_t)(b * Hh + h);
  const unsigned short* Qb = Qg + bh * NP * 64;
  const unsigned short* Kb = Kg + bh * NP * 64;
  const unsigned short* Vb = Vg + bh * 64 * NP;
  int i0 = ib * 64 + w * 16;
  int irow = i0 + lm;
  const unsigned short* Mrow = Mg + (size_t)b * NP * NP + (size_t)irow * NP;

  bfrag qf0 = *(const bfrag*)(Qb + (size_t)irow * 64 + 8 * lg);
  bfrag qf1 = *(const bfrag*)(Qb + (size_t)irow * 64 + 32 + 8 * lg);

  ffrag zero4 = {0.f, 0.f, 0.f, 0.f};
  ffrag oacc[4] = {zero4, zero4, zero4, zero4};
  float Tp = 0.f;

  // staging: thread covers chunks c=tid (row rS) and c=tid+256 (row rS+32);
  // LDS slot p of row r holds global chunk p^(r&7) -> pre-swizzled global addr, linear LDS dest.
  int rS = tid >> 3, pS = tid & 7;
  int rS2 = rS + 32;
  const unsigned short* kS0 = Kb + (size_t)rS * 64 + 8 * (pS ^ (rS & 7));
  const unsigned short* kS1 = Kb + (size_t)rS2 * 64 + 8 * (pS ^ (rS2 & 7));
  const unsigned short* vS0 = Vb + (size_t)rS * NP + 8 * (pS ^ (rS & 7));
  const unsigned short* vS1 = Vb + (size_t)rS2 * NP + 8 * (pS ^ (rS2 & 7));

  char* Pbase = (char*)(smem + 2048) + w * 2048;   // per-wave P tile [16 i][64 j] bf16, chunk-XOR

  // prologue: stage tile 0 into buffer 0; prefetch mask tile 0
  gload16(kS0, smem + tid);
  gload16(kS1, smem + tid + 256);
  gload16(vS0, smem + 1024 + tid);
  gload16(vS1, smem + 1024 + tid + 256);
  us4 mva[4], mvb[4];
#pragma unroll
  for (int jm = 0; jm < 4; jm++) mva[jm] = *(const us4*)(Mrow + 16 * jm + 4 * lg);
  asm volatile("s_waitcnt vmcnt(0)" ::: "memory");
  __builtin_amdgcn_sched_barrier(0);
  __builtin_amdgcn_s_barrier();

#pragma unroll 1
  for (int t = 0; t < 17; t++) {
    int cb = (t & 1) << 9;
    if (t < 16) {
      int nb = ((t + 1) & 1) << 9;
      size_t ko = (size_t)(t + 1) * 4096;   // K advances 64 rows * 64 elems
      int vo = (t + 1) * 64;                // V^T advances 64 columns
      gload16(kS0 + ko, smem + nb + tid);
      gload16(kS1 + ko, smem + nb + tid + 256);
      gload16(vS0 + vo, smem + 1024 + nb + tid);
      gload16(vS1 + vo, smem + 1024 + nb + tid + 256);
#pragma unroll
      for (int jm = 0; jm < 4; jm++) mvb[jm] = *(const us4*)(Mrow + (t + 1) * 64 + 16 * jm + 4 * lg);
    }
    const bfrag* LK = (const bfrag*)(smem + cb);
    const bfrag* LV = (const bfrag*)(smem + 1024 + cb);

    // --- QK^T (swapped): s[jm][r] = S[j0+16jm+4lg+r][i0+lm] ---
    ffrag s[4];
    __builtin_amdgcn_s_setprio(1);
#pragma unroll
    for (int jm = 0; jm < 4; jm++) {
      int row = jm * 16 + lm;
      bfrag a0 = LK[row * 8 + ((0 + lg) ^ (row & 7))];
      bfrag a1 = LK[row * 8 + ((4 + lg) ^ (row & 7))];
      ffrag a = zero4;
      a = MFMA16(a0, qf0, a);
      a = MFMA16(a1, qf1, a);
      s[jm] = a;
    }
    __builtin_amdgcn_s_setprio(0);
    // --- p = exp2(s); pm = p*mask; accumulate T; pack + write P ---
#pragma unroll
    for (int jm = 0; jm < 4; jm++) {
      float p0 = EXP2(s[jm][0]), p1 = EXP2(s[jm][1]), p2 = EXP2(s[jm][2]), p3 = EXP2(s[jm][3]);
      float q0 = p0 * bf2f(mva[jm][0]), q1 = p1 * bf2f(mva[jm][1]);
      float q2 = p2 * bf2f(mva[jm][2]), q3 = p3 * bf2f(mva[jm][3]);
      Tp += (q0 + q1) + (q2 + q3);
      uint2 pk; pk.x = pkbf(q0, q1); pk.y = pkbf(q2, q3);
      int cpos = (((jm << 1) | (lg >> 1)) ^ (lm & 7));
      *(uint2*)(Pbase + lm * 128 + cpos * 16 + 8 * (lg & 1)) = pk;
    }
    // --- PV: A = P[16i][64j] (chunk-XOR read), B = V^T rows from LDS ---
    __builtin_amdgcn_s_setprio(1);
#pragma unroll
    for (int ks = 0; ks < 2; ks++) {
      bfrag pa = *(const bfrag*)(Pbase + lm * 128 + ((((ks << 2) | lg)) ^ (lm & 7)) * 16);
#pragma unroll
      for (int dm = 0; dm < 4; dm++) {
        int vrow = dm * 16 + lm;
        bfrag vb = LV[vrow * 8 + ((ks * 4 + lg) ^ (vrow & 7))];
        oacc[dm] = MFMA16(pa, vb, oacc[dm]);
      }
    }
    __builtin_amdgcn_s_setprio(0);
#pragma unroll
    for (int jm = 0; jm < 4; jm++) mva[jm] = mvb[jm];
    // next tile's K/V landed; all waves done reading current buffers.
    asm volatile("s_waitcnt vmcnt(0)" ::: "memory");
    __builtin_amdgcn_sched_barrier(0);
    __builtin_amdgcn_s_barrier();
  }
  // --- finalize: reduce T across lg lanes; broadcast per-row denominators ---
  Tp += __shfl_xor(Tp, 16); Tp += __shfl_xor(Tp, 32);
  float dn_row = 1.f / Tp;   // valid at every lane for row i0 + lm (eps*Z dropped: rel ~2e-6)
  float dn[4];
#pragma unroll
  for (int r = 0; r < 4; r++) dn[r] = __shfl(dn_row, 4 * lg + r);  // row of oacc reg r
#pragma unroll
  for (int dm = 0; dm < 4; dm++)
#pragma unroll
    for (int r = 0; r < 4; r++) {
      int i = i0 + 4 * lg + r;
      if (i < Nn) Og[((size_t)(b * Nn + i)) * Dd + h * 64 + dm * 16 + lm] = f2bf(oacc[dm][r] * dn[r]);
    }
}

// ---------------- launch ----------------
extern "C" void kernel_launch(void* const* d_in, const int* in_sizes, int n_in,
                              void* d_out, int out_size, void* d_ws, size_t ws_size,
                              hipStream_t stream) {
  const float* x      = (const float*)d_in[0];
  const float* graph  = (const float*)d_in[1];
  const float* transf = (const float*)d_in[2];
  const float* Wqkv   = (const float*)d_in[3];
  const float* bqkv   = (const float*)d_in[4];
  const float* Wproj  = (const float*)d_in[5];
  const float* bproj  = (const float*)d_in[6];
  float* out = (float*)d_out;
  char* ws = (char*)d_ws;

  // ws layout (bytes); total ~76.4 MB. attn_out aliases x_bf16 (disjoint lifetimes).
  unsigned short* xbf  = (unsigned short*)(ws + 0);                 // 12,595,200 (also attn_out)
  unsigned short* wqb  = (unsigned short*)(ws + 12595200);          //  3,538,944
  unsigned short* wpb  = (unsigned short*)(ws + 16134144);          //  1,179,648
  unsigned short* Qb   = (unsigned short*)(ws + 17313792);          // 13,369,344
  unsigned short* Kb   = (unsigned short*)(ws + 30683136);          // 13,369,344
  unsigned short* Vb   = (unsigned short*)(ws + 44052480);          // 13,369,344
  float*          pw   = (float*)(ws + 57421824);                   //     32,768
  unsigned short* mask = (unsigned short*)(ws + 57454592);          // 18,939,904
  unsigned short* aob  = xbf;  // attention output bf16 [8200][768]

  conv_kernel<<<2048, 256, 0, stream>>>(x, xbf, (MROWS * Dd) / 4);
  conv_kernel<<<1728, 256, 0, stream>>>(Wqkv, wqb, (3 * Dd * Dd) / 4);
  conv_kernel<<<576, 256, 0, stream>>>(Wproj, wpb, (Dd * Dd) / 4);
  pw_kernel<<<Bq, 256, 0, stream>>>(transf, pw);
  mask_kernel<<<dim3(NP, Bq), 256, 0, stream>>>(graph, pw, mask);
  padzero_kernel<<<96, 256, 0, stream>>>(Qb, Kb, Vb);
  qkv_gemm_kernel<<<65 * 18, 256, 0, stream>>>(xbf, wqb, bqkv, Qb, Kb, Vb);
  attn_kernel<<<1632, 256, 0, stream>>>(Qb, Kb, Vb, mask, aob);
  proj_gemm_kernel<<<65 * 6, 256, 0, stream>>>(aob, wpb, bproj, out);
}